// Round 1
// baseline (1304.826 us; speedup 1.0000x reference)
//
#include <hip/hip_runtime.h>
#include <hip/hip_bf16.h>

#define HF 128
#define GG 128
#define CC 10
#define EPS 1e-5f

// ---------------- graph build ----------------
__global__ void k_count(const int* __restrict__ ei, int E, int* cs, int* cd) {
    int e = blockIdx.x * 256 + threadIdx.x;
    if (e < E) {
        atomicAdd(&cs[ei[e]], 1);        // out-degree (src)
        atomicAdd(&cd[ei[E + e]], 1);    // in-degree (dst) for CSR
    }
}

__global__ void k_dis(const int* __restrict__ cs, float* dis, int n) {
    int i = blockIdx.x * 256 + threadIdx.x;
    if (i < n) dis[i] = rsqrtf((float)(1 + cs[i]));  // deg includes self-loop
}

__global__ void k_scan1(const int* __restrict__ cd, int* offs, int* bsum, int n) {
    __shared__ int sh[256];
    int t = threadIdx.x, i = blockIdx.x * 256 + t;
    int v = (i < n) ? cd[i] : 0;
    sh[t] = v; __syncthreads();
    for (int o = 1; o < 256; o <<= 1) {
        int x = (t >= o) ? sh[t - o] : 0;
        __syncthreads();
        sh[t] += x;
        __syncthreads();
    }
    if (i < n) offs[i] = sh[t] - v;          // exclusive within block
    if (t == 255) bsum[blockIdx.x] = sh[255];
}

__global__ void k_scan2(const int* __restrict__ bsum, int* bscan, int nb) {
    __shared__ int sh[256];
    int t = threadIdx.x;
    int v = (t < nb) ? bsum[t] : 0;
    sh[t] = v; __syncthreads();
    for (int o = 1; o < 256; o <<= 1) {
        int x = (t >= o) ? sh[t - o] : 0;
        __syncthreads();
        sh[t] += x;
        __syncthreads();
    }
    if (t < nb) bscan[t] = sh[t] - v;
}

__global__ void k_scan3(int* offs, const int* __restrict__ bscan, int* cursor, int n) {
    int i = blockIdx.x * 256 + threadIdx.x;
    if (i < n) {
        int v = offs[i] + bscan[blockIdx.x];
        offs[i] = v;
        cursor[i] = v;
    }
}

__global__ void k_fill(const int* __restrict__ ei, int E, const float* __restrict__ dis,
                       int* cursor, int* eSrc, float* eW) {
    int e = blockIdx.x * 256 + threadIdx.x;
    if (e < E) {
        int s = ei[e], d = ei[E + e];
        int p = atomicAdd(&cursor[d], 1);
        eSrc[p] = s;
        eW[p] = dis[s] * dis[d];
    }
}

// ---------------- BN stats / fold ----------------
__global__ void k_colstats(const float* __restrict__ X, float* stats, int n) {
    int c = threadIdx.x & 127, rl = threadIdx.x >> 7;
    float s = 0.f, q = 0.f;
    for (int i = blockIdx.x * 2 + rl; i < n; i += gridDim.x * 2) {
        float v = X[(size_t)i * HF + c];
        s += v; q += v * v;
    }
    __shared__ float sh[512];
    sh[threadIdx.x] = s; sh[256 + threadIdx.x] = q;
    __syncthreads();
    if (threadIdx.x < 128) {
        atomicAdd(&stats[c],      sh[threadIdx.x] + sh[threadIdx.x + 128]);
        atomicAdd(&stats[HF + c], sh[256 + threadIdx.x] + sh[256 + threadIdx.x + 128]);
    }
}

__global__ void k_scaleshift(const float* __restrict__ stats, const float* __restrict__ g,
                             const float* __restrict__ b, float* ss, float cntInv) {
    int c = threadIdx.x;
    float mean = stats[c] * cntInv;
    float var = stats[HF + c] * cntInv - mean * mean;
    float sc = g[c] * rsqrtf(var + EPS);
    ss[c] = sc;
    ss[HF + c] = b[c] - mean * sc;
}

// blocks 0..127: scale W rows; block 128: bias = shift @ W
__global__ void k_fold(const float* __restrict__ W, const float* __restrict__ ss,
                       float* Wt, float* biasT) {
    int c = threadIdx.x;
    if (blockIdx.x < HF) {
        int k = blockIdx.x;
        Wt[k * HF + c] = ss[k] * W[k * HF + c];
    } else {
        float acc = 0.f;
        for (int k = 0; k < HF; k++) acc += ss[HF + k] * W[k * HF + c];
        biasT[c] = acc;
    }
}

// ---------------- GEMM (N x 128) @ (128 x 128) + bias (+relu) (+column stats) ----------------
template <int RELU, int STATS>
__global__ __launch_bounds__(256) void k_gemm(const float* __restrict__ A,
                                              const float* __restrict__ Wt,
                                              const float* __restrict__ biasT,
                                              float* __restrict__ out, int n, float* stats) {
    __shared__ float Ws[HF * HF];          // 64 KB
    float4* Ws4 = (float4*)Ws;
    const float4* W4 = (const float4*)Wt;
    for (int i = threadIdx.x; i < HF * HF / 4; i += 256) Ws4[i] = W4[i];
    __syncthreads();

    int tx = threadIdx.x & 31, ty = threadIdx.x >> 5;
    int r0 = blockIdx.x * 64 + ty * 8;
    const float4* A4 = (const float4*)A;

    float4 acc[8];
#pragma unroll
    for (int r = 0; r < 8; r++) acc[r] = make_float4(0.f, 0.f, 0.f, 0.f);

    for (int kc = 0; kc < 32; kc++) {
        float4 a[8];
#pragma unroll
        for (int r = 0; r < 8; r++) {
            int row = r0 + r;
            a[r] = (row < n) ? A4[(size_t)row * 32 + kc] : make_float4(0.f, 0.f, 0.f, 0.f);
        }
#pragma unroll
        for (int j = 0; j < 4; j++) {
            float4 wv = Ws4[(kc * 4 + j) * 32 + tx];
#pragma unroll
            for (int r = 0; r < 8; r++) {
                float av = (j == 0) ? a[r].x : (j == 1) ? a[r].y : (j == 2) ? a[r].z : a[r].w;
                acc[r].x += av * wv.x;
                acc[r].y += av * wv.y;
                acc[r].z += av * wv.z;
                acc[r].w += av * wv.w;
            }
        }
    }

    float4 bv = ((const float4*)biasT)[tx];
    float s[4] = {0.f, 0.f, 0.f, 0.f}, q[4] = {0.f, 0.f, 0.f, 0.f};
    float4* O4 = (float4*)out;
#pragma unroll
    for (int r = 0; r < 8; r++) {
        int row = r0 + r;
        if (row < n) {
            float4 v;
            v.x = acc[r].x + bv.x; v.y = acc[r].y + bv.y;
            v.z = acc[r].z + bv.z; v.w = acc[r].w + bv.w;
            if (RELU) {
                v.x = fmaxf(v.x, 0.f); v.y = fmaxf(v.y, 0.f);
                v.z = fmaxf(v.z, 0.f); v.w = fmaxf(v.w, 0.f);
            }
            O4[(size_t)row * 32 + tx] = v;
            if (STATS) {
                s[0] += v.x; q[0] += v.x * v.x;
                s[1] += v.y; q[1] += v.y * v.y;
                s[2] += v.z; q[2] += v.z * v.z;
                s[3] += v.w; q[3] += v.w * v.w;
            }
        }
    }
    if (STATS) {
        __syncthreads();   // done with Ws, reuse as reduction scratch
#pragma unroll
        for (int j = 0; j < 4; j++) {
            Ws[threadIdx.x * 4 + j] = s[j];
            Ws[4096 + threadIdx.x * 4 + j] = q[j];
        }
        __syncthreads();
        if (threadIdx.x < 32) {
#pragma unroll
            for (int j = 0; j < 4; j++) {
                float ts = 0.f, tq = 0.f;
                for (int g = 0; g < 8; g++) {
                    ts += Ws[(g * 32 + threadIdx.x) * 4 + j];
                    tq += Ws[4096 + (g * 32 + threadIdx.x) * 4 + j];
                }
                atomicAdd(&stats[threadIdx.x * 4 + j], ts);
                atomicAdd(&stats[HF + threadIdx.x * 4 + j], tq);
            }
        }
    }
}

// ---------------- aggregation: out[i] = relu(dis2*y[i] + sum_e w*y[src] + conv_b) ----------------
template <int STATS>
__global__ __launch_bounds__(256) void k_agg(const float* __restrict__ B,
                                             const int* __restrict__ eSrc,
                                             const float* __restrict__ eW,
                                             const int* __restrict__ offs,
                                             const int* __restrict__ cnt,
                                             const float* __restrict__ dis,
                                             const float* __restrict__ convb,
                                             float* __restrict__ out, float* stats, int n) {
    int c = threadIdx.x & 127, local = threadIdx.x >> 7;
    float bb = convb[c];
    float ssum = 0.f, sq = 0.f;
    int base = blockIdx.x * 16;
    for (int p = 0; p < 8; p++) {
        int i = base + p * 2 + local;
        if (i < n) {
            float d = dis[i];
            float acc = d * d * B[(size_t)i * HF + c];
            int s0 = offs[i], e0 = s0 + cnt[i];
            for (int j = s0; j < e0; j++) {
                acc += eW[j] * B[(size_t)eSrc[j] * HF + c];
            }
            float v = fmaxf(acc + bb, 0.f);
            out[(size_t)i * HF + c] = v;
            if (STATS) { ssum += v; sq += v * v; }
        }
    }
    if (STATS) {
        __shared__ float sh[512];
        sh[threadIdx.x] = ssum; sh[256 + threadIdx.x] = sq;
        __syncthreads();
        if (threadIdx.x < 128) {
            atomicAdd(&stats[c],      sh[threadIdx.x] + sh[threadIdx.x + 128]);
            atomicAdd(&stats[HF + c], sh[256 + threadIdx.x] + sh[256 + threadIdx.x + 128]);
        }
    }
}

// ---------------- global add pool (batch sorted -> run accumulation) ----------------
__global__ void k_pool(const float* __restrict__ A, const int* __restrict__ batch,
                       float* gpool, int n) {
    int c = threadIdx.x;
    int s = blockIdx.x * 256, e = min(s + 256, n);
    if (s >= n) return;
    float acc = 0.f;
    int cur = batch[s];
    for (int i = s; i < e; i++) {
        int b = batch[i];
        if (b != cur) {
            atomicAdd(&gpool[cur * HF + c], acc);
            acc = 0.f; cur = b;
        }
        acc += A[(size_t)i * HF + c];
    }
    atomicAdd(&gpool[cur * HF + c], acc);
}

// ---------------- head ----------------
__global__ void k_bnsmall(const float* __restrict__ in, const float* __restrict__ g,
                          const float* __restrict__ b, float* out) {
    int c = threadIdx.x;
    float s = 0.f, q = 0.f;
    for (int r = 0; r < GG; r++) { float v = in[r * HF + c]; s += v; q += v * v; }
    float mean = s / GG;
    float var = q / GG - mean * mean;
    float sc = g[c] * rsqrtf(var + EPS), sh = b[c] - mean * sc;
    for (int r = 0; r < GG; r++) out[r * HF + c] = in[r * HF + c] * sc + sh;
}

__global__ void k_fc(const float* __restrict__ Gbn, const float* __restrict__ Wfc,
                     const float* __restrict__ bfc, float* __restrict__ G2) {
    __shared__ float row[HF];
    int c = threadIdx.x, r = blockIdx.x;
    row[c] = Gbn[r * HF + c];
    __syncthreads();
    float acc = bfc[c];
    for (int k = 0; k < HF; k++) acc += row[k] * Wfc[k * HF + c];
    G2[r * HF + c] = fmaxf(acc, 0.f);
}

__global__ void k_head2(const float* __restrict__ G2, const float* __restrict__ g,
                        const float* __restrict__ b, const float* __restrict__ Wcls,
                        const float* __restrict__ bcls, float* __restrict__ scratch,
                        float* __restrict__ outp) {
    __shared__ float Ls[GG * HF];  // 64 KB
    int c = threadIdx.x;
    float s = 0.f, q = 0.f;
    for (int r = 0; r < GG; r++) { float v = G2[r * HF + c]; s += v; q += v * v; }
    float mean = s / GG;
    float var = q / GG - mean * mean;
    float sc = g[c] * rsqrtf(var + EPS), sh = b[c] - mean * sc;
    for (int r = 0; r < GG; r++) Ls[r * HF + c] = G2[r * HF + c] * sc + sh;
    __syncthreads();
    for (int o = c; o < GG * CC; o += HF) {
        int r = o / CC, j = o % CC;
        float acc = bcls[j];
        for (int k = 0; k < HF; k++) acc += Ls[r * HF + k] * Wcls[k * CC + j];
        scratch[o] = acc;
    }
    __threadfence_block();
    __syncthreads();
    int r = c;  // 128 threads == GG rows
    float m = -1e30f;
    for (int j = 0; j < CC; j++) m = fmaxf(m, scratch[r * CC + j]);
    float se = 0.f;
    for (int j = 0; j < CC; j++) se += expf(scratch[r * CC + j] - m);
    float ls = logf(se);
    for (int j = 0; j < CC; j++) outp[r * CC + j] = scratch[r * CC + j] - m - ls;
}

extern "C" void kernel_launch(void* const* d_in, const int* in_sizes, int n_in,
                              void* d_out, int out_size, void* d_ws, size_t ws_size,
                              hipStream_t stream) {
    const float* x         = (const float*)d_in[0];
    const int*   ei        = (const int*)d_in[1];
    const int*   batch     = (const int*)d_in[2];
    const float* bn_feat_g = (const float*)d_in[3];
    const float* bn_feat_b = (const float*)d_in[4];
    const float* W_feat    = (const float*)d_in[5];
    const float* conv_bn_g = (const float*)d_in[6];
    const float* conv_bn_b = (const float*)d_in[7];
    const float* conv_W    = (const float*)d_in[8];
    const float* conv_b    = (const float*)d_in[9];
    const float* bn_fc_g   = (const float*)d_in[10];
    const float* bn_fc_b   = (const float*)d_in[11];
    const float* W_fc      = (const float*)d_in[12];
    const float* b_fc      = (const float*)d_in[13];
    const float* bn_hid_g  = (const float*)d_in[14];
    const float* bn_hid_b  = (const float*)d_in[15];
    const float* W_cls     = (const float*)d_in[16];
    const float* b_cls     = (const float*)d_in[17];
    float* outp = (float*)d_out;

    int N = in_sizes[0] / HF;
    int E = in_sizes[1] / 2;

    char* w = (char*)d_ws;
    size_t off = 0;
    auto al = [&](size_t bytes) -> void* {
        off = (off + 255) & ~(size_t)255;
        void* p = w + off;
        off += bytes;
        return p;
    };
    float* A      = (float*)al((size_t)N * HF * 4);
    float* Bf     = (float*)al((size_t)N * HF * 4);
    int*   eSrc   = (int*)al((size_t)E * 4);
    float* eWt    = (float*)al((size_t)E * 4);
    float* dis    = (float*)al((size_t)N * 4);
    int*   offsb  = (int*)al((size_t)N * 4);
    int*   cursor = (int*)al((size_t)N * 4);
    float* Wt     = (float*)al(HF * HF * 4);
    float* biasT  = (float*)al(HF * 4);
    float* ss     = (float*)al(2 * HF * 4);
    int*   bsum   = (int*)al(1024);
    int*   bscan  = (int*)al(1024);
    float* Gbn    = (float*)al(GG * HF * 4);
    float* G2     = (float*)al(GG * HF * 4);
    // zeroed region
    size_t z0 = (off + 255) & ~(size_t)255;
    off = z0;
    int*   cs    = (int*)al((size_t)N * 4);
    int*   cd    = (int*)al((size_t)N * 4);
    float* Sx    = (float*)al(2 * HF * 4);
    float* S0    = (float*)al(2 * HF * 4);
    float* S1    = (float*)al(2 * HF * 4);
    float* S2    = (float*)al(2 * HF * 4);
    float* gpool = (float*)al(GG * HF * 4);
    size_t zbytes = off - z0;
    hipMemsetAsync(w + z0, 0, zbytes, stream);

    int nbE = (E + 255) / 256;
    int nbN = (N + 255) / 256;

    // graph build
    k_count<<<nbE, 256, 0, stream>>>(ei, E, cs, cd);
    k_dis<<<nbN, 256, 0, stream>>>(cs, dis, N);
    k_scan1<<<nbN, 256, 0, stream>>>(cd, offsb, bsum, N);
    k_scan2<<<1, 256, 0, stream>>>(bsum, bscan, nbN);
    k_scan3<<<nbN, 256, 0, stream>>>(offsb, bscan, cursor, N);
    k_fill<<<nbE, 256, 0, stream>>>(ei, E, dis, cursor, eSrc, eWt);

    // BN(x) stats
    k_colstats<<<400, 256, 0, stream>>>(x, Sx, N);

    // feat layer: h0 = relu(bn(x) @ W_feat), fused stats -> S0
    k_scaleshift<<<1, HF, 0, stream>>>(Sx, bn_feat_g, bn_feat_b, ss, 1.0f / N);
    k_fold<<<HF + 1, HF, 0, stream>>>(W_feat, ss, Wt, biasT);
    k_gemm<1, 1><<<(N + 63) / 64, 256, 0, stream>>>(x, Wt, biasT, A, N, S0);

    float* Sarr[3] = {S0, S1, S2};
    for (int i = 0; i < 3; i++) {
        k_scaleshift<<<1, HF, 0, stream>>>(Sarr[i], conv_bn_g + i * HF, conv_bn_b + i * HF, ss, 1.0f / N);
        k_fold<<<HF + 1, HF, 0, stream>>>(conv_W + (size_t)i * HF * HF, ss, Wt, biasT);
        k_gemm<0, 0><<<(N + 63) / 64, 256, 0, stream>>>(A, Wt, biasT, Bf, N, nullptr);
        if (i < 2)
            k_agg<1><<<(N + 15) / 16, 256, 0, stream>>>(Bf, eSrc, eWt, offsb, cd, dis,
                                                        conv_b + i * HF, A, Sarr[i + 1], N);
        else
            k_agg<0><<<(N + 15) / 16, 256, 0, stream>>>(Bf, eSrc, eWt, offsb, cd, dis,
                                                        conv_b + i * HF, A, nullptr, N);
    }

    // pool + head
    k_pool<<<(N + 255) / 256, HF, 0, stream>>>(A, batch, gpool, N);
    k_bnsmall<<<1, HF, 0, stream>>>(gpool, bn_fc_g, bn_fc_b, Gbn);
    k_fc<<<GG, HF, 0, stream>>>(Gbn, W_fc, b_fc, G2);
    k_head2<<<1, HF, 0, stream>>>(G2, bn_hid_g, bn_hid_b, W_cls, b_cls, Gbn, outp);
}

// Round 2
// 900.772 us; speedup vs baseline: 1.4486x; 1.4486x over previous
//
#include <hip/hip_runtime.h>
#include <hip/hip_bf16.h>

#define HF 128
#define GG 128
#define CC 10
#define EPS 1e-5f

__device__ inline unsigned short f2bf(float f) {
    unsigned int u = __float_as_uint(f);
    return (unsigned short)((u + 0x7FFFu + ((u >> 16) & 1u)) >> 16);
}

__device__ inline void bfacc(float* acc, uint4 u, float w) {
    acc[0] = fmaf(w, __uint_as_float(u.x << 16), acc[0]);
    acc[1] = fmaf(w, __uint_as_float(u.x & 0xFFFF0000u), acc[1]);
    acc[2] = fmaf(w, __uint_as_float(u.y << 16), acc[2]);
    acc[3] = fmaf(w, __uint_as_float(u.y & 0xFFFF0000u), acc[3]);
    acc[4] = fmaf(w, __uint_as_float(u.z << 16), acc[4]);
    acc[5] = fmaf(w, __uint_as_float(u.z & 0xFFFF0000u), acc[5]);
    acc[6] = fmaf(w, __uint_as_float(u.w << 16), acc[6]);
    acc[7] = fmaf(w, __uint_as_float(u.w & 0xFFFF0000u), acc[7]);
}

// ---------------- graph build ----------------
__global__ void k_count(const int* __restrict__ ei, int E, int* cs, int* cd) {
    int e = blockIdx.x * 256 + threadIdx.x;
    if (e < E) {
        atomicAdd(&cs[ei[e]], 1);        // out-degree (src)
        atomicAdd(&cd[ei[E + e]], 1);    // in-degree (dst) for CSR
    }
}

__global__ void k_dis(const int* __restrict__ cs, float* dis, int n) {
    int i = blockIdx.x * 256 + threadIdx.x;
    if (i < n) dis[i] = rsqrtf((float)(1 + cs[i]));  // deg includes self-loop
}

__global__ void k_scan1(const int* __restrict__ cd, int* offs, int* bsum, int n) {
    __shared__ int sh[256];
    int t = threadIdx.x, i = blockIdx.x * 256 + t;
    int v = (i < n) ? cd[i] : 0;
    sh[t] = v; __syncthreads();
    for (int o = 1; o < 256; o <<= 1) {
        int x = (t >= o) ? sh[t - o] : 0;
        __syncthreads();
        sh[t] += x;
        __syncthreads();
    }
    if (i < n) offs[i] = sh[t] - v;          // exclusive within block
    if (t == 255) bsum[blockIdx.x] = sh[255];
}

__global__ void k_scan2(const int* __restrict__ bsum, int* bscan, int nb) {
    __shared__ int sh[256];
    int t = threadIdx.x;
    int v = (t < nb) ? bsum[t] : 0;
    sh[t] = v; __syncthreads();
    for (int o = 1; o < 256; o <<= 1) {
        int x = (t >= o) ? sh[t - o] : 0;
        __syncthreads();
        sh[t] += x;
        __syncthreads();
    }
    if (t < nb) bscan[t] = sh[t] - v;
}

__global__ void k_scan3(int* offs, const int* __restrict__ bscan, int* cursor, int n) {
    int i = blockIdx.x * 256 + threadIdx.x;
    if (i < n) {
        int v = offs[i] + bscan[blockIdx.x];
        offs[i] = v;
        cursor[i] = v;
    }
}

__global__ void k_fill(const int* __restrict__ ei, int E, const float* __restrict__ dis,
                       int* cursor, int* eSrc, float* eW) {
    int e = blockIdx.x * 256 + threadIdx.x;
    if (e < E) {
        int s = ei[e], d = ei[E + e];
        int p = atomicAdd(&cursor[d], 1);
        eSrc[p] = s;
        eW[p] = dis[s] * dis[d];
    }
}

// ---------------- BN stats / fold ----------------
__global__ void k_colstats(const float* __restrict__ X, float* stats, int n) {
    int c = threadIdx.x & 127, rl = threadIdx.x >> 7;
    float s = 0.f, q = 0.f;
    for (int i = blockIdx.x * 2 + rl; i < n; i += gridDim.x * 2) {
        float v = X[(size_t)i * HF + c];
        s += v; q += v * v;
    }
    __shared__ float sh[512];
    sh[threadIdx.x] = s; sh[256 + threadIdx.x] = q;
    __syncthreads();
    if (threadIdx.x < 128) {
        atomicAdd(&stats[c],      sh[threadIdx.x] + sh[threadIdx.x + 128]);
        atomicAdd(&stats[HF + c], sh[256 + threadIdx.x] + sh[256 + threadIdx.x + 128]);
    }
}

__global__ void k_scaleshift(const float* __restrict__ stats, const float* __restrict__ g,
                             const float* __restrict__ b, float* ss, float cntInv) {
    int c = threadIdx.x;
    float mean = stats[c] * cntInv;
    float var = stats[HF + c] * cntInv - mean * mean;
    float sc = g[c] * rsqrtf(var + EPS);
    ss[c] = sc;
    ss[HF + c] = b[c] - mean * sc;
}

// blocks 0..127: scale W rows; block 128: bias = shift @ W
__global__ void k_fold(const float* __restrict__ W, const float* __restrict__ ss,
                       float* Wt, float* biasT) {
    int c = threadIdx.x;
    if (blockIdx.x < HF) {
        int k = blockIdx.x;
        Wt[k * HF + c] = ss[k] * W[k * HF + c];
    } else {
        float acc = 0.f;
        for (int k = 0; k < HF; k++) acc += ss[HF + k] * W[k * HF + c];
        biasT[c] = acc;
    }
}

// ---------------- GEMM (N x 128) @ (128 x 128) + bias (+relu) (+column stats) ----------------
template <int RELU, int STATS, int OUTBF>
__global__ __launch_bounds__(256) void k_gemm(const float* __restrict__ A,
                                              const float* __restrict__ Wt,
                                              const float* __restrict__ biasT,
                                              void* __restrict__ outv, int n, float* stats) {
    __shared__ float Ws[HF * HF];          // 64 KB
    float4* Ws4 = (float4*)Ws;
    const float4* W4 = (const float4*)Wt;
    for (int i = threadIdx.x; i < HF * HF / 4; i += 256) Ws4[i] = W4[i];
    __syncthreads();

    int tx = threadIdx.x & 31, ty = threadIdx.x >> 5;
    int r0 = blockIdx.x * 64 + ty * 8;
    const float4* A4 = (const float4*)A;

    float4 acc[8];
#pragma unroll
    for (int r = 0; r < 8; r++) acc[r] = make_float4(0.f, 0.f, 0.f, 0.f);

    for (int kc = 0; kc < 32; kc++) {
        float4 a[8];
#pragma unroll
        for (int r = 0; r < 8; r++) {
            int row = r0 + r;
            a[r] = (row < n) ? A4[(size_t)row * 32 + kc] : make_float4(0.f, 0.f, 0.f, 0.f);
        }
#pragma unroll
        for (int j = 0; j < 4; j++) {
            float4 wv = Ws4[(kc * 4 + j) * 32 + tx];
#pragma unroll
            for (int r = 0; r < 8; r++) {
                float av = (j == 0) ? a[r].x : (j == 1) ? a[r].y : (j == 2) ? a[r].z : a[r].w;
                acc[r].x += av * wv.x;
                acc[r].y += av * wv.y;
                acc[r].z += av * wv.z;
                acc[r].w += av * wv.w;
            }
        }
    }

    float4 bv = ((const float4*)biasT)[tx];
    float s[4] = {0.f, 0.f, 0.f, 0.f}, q[4] = {0.f, 0.f, 0.f, 0.f};
#pragma unroll
    for (int r = 0; r < 8; r++) {
        int row = r0 + r;
        if (row < n) {
            float4 v;
            v.x = acc[r].x + bv.x; v.y = acc[r].y + bv.y;
            v.z = acc[r].z + bv.z; v.w = acc[r].w + bv.w;
            if (RELU) {
                v.x = fmaxf(v.x, 0.f); v.y = fmaxf(v.y, 0.f);
                v.z = fmaxf(v.z, 0.f); v.w = fmaxf(v.w, 0.f);
            }
            if (OUTBF) {
                ushort4 o;
                o.x = f2bf(v.x); o.y = f2bf(v.y); o.z = f2bf(v.z); o.w = f2bf(v.w);
                ((ushort4*)outv)[(size_t)row * 32 + tx] = o;
            } else {
                ((float4*)outv)[(size_t)row * 32 + tx] = v;
            }
            if (STATS) {
                s[0] += v.x; q[0] += v.x * v.x;
                s[1] += v.y; q[1] += v.y * v.y;
                s[2] += v.z; q[2] += v.z * v.z;
                s[3] += v.w; q[3] += v.w * v.w;
            }
        }
    }
    if (STATS) {
        __syncthreads();   // done with Ws, reuse as reduction scratch
#pragma unroll
        for (int j = 0; j < 4; j++) {
            Ws[threadIdx.x * 4 + j] = s[j];
            Ws[4096 + threadIdx.x * 4 + j] = q[j];
        }
        __syncthreads();
        if (threadIdx.x < 32) {
#pragma unroll
            for (int j = 0; j < 4; j++) {
                float ts = 0.f, tq = 0.f;
                for (int g = 0; g < 8; g++) {
                    ts += Ws[(g * 32 + threadIdx.x) * 4 + j];
                    tq += Ws[4096 + (g * 32 + threadIdx.x) * 4 + j];
                }
                atomicAdd(&stats[threadIdx.x * 4 + j], ts);
                atomicAdd(&stats[HF + threadIdx.x * 4 + j], tq);
            }
        }
    }
}

// ------- aggregation: out[i] = relu(dis2*y[i] + sum_e w*y[src] + conv_b), y in bf16 -------
// 16 lanes per node, 8 channels (one uint4 = 8 bf16) per lane; 16 nodes per block.
template <int STATS>
__global__ __launch_bounds__(256) void k_agg(const unsigned short* __restrict__ B,
                                             const int* __restrict__ eSrc,
                                             const float* __restrict__ eW,
                                             const int* __restrict__ offs,
                                             const int* __restrict__ cnt,
                                             const float* __restrict__ dis,
                                             const float* __restrict__ convb,
                                             float* __restrict__ out, float* stats, int n) {
    int t = threadIdx.x;
    int lg = t & 15;
    int node = blockIdx.x * 16 + (t >> 4);
    const uint4* Bv = (const uint4*)B;
    float acc[8] = {0.f, 0.f, 0.f, 0.f, 0.f, 0.f, 0.f, 0.f};
    float v[8];
    if (node < n) {
        float d = dis[node];
        uint4 us = Bv[(size_t)node * 16 + lg];
        bfacc(acc, us, d * d);
        int j = offs[node], e0 = j + cnt[node];
        for (; j + 4 <= e0; j += 4) {
            int i0 = eSrc[j], i1 = eSrc[j + 1], i2 = eSrc[j + 2], i3 = eSrc[j + 3];
            float w0 = eW[j], w1 = eW[j + 1], w2 = eW[j + 2], w3 = eW[j + 3];
            uint4 u0 = Bv[(size_t)i0 * 16 + lg];
            uint4 u1 = Bv[(size_t)i1 * 16 + lg];
            uint4 u2 = Bv[(size_t)i2 * 16 + lg];
            uint4 u3 = Bv[(size_t)i3 * 16 + lg];
            bfacc(acc, u0, w0); bfacc(acc, u1, w1);
            bfacc(acc, u2, w2); bfacc(acc, u3, w3);
        }
        for (; j < e0; j++) {
            uint4 u0 = Bv[(size_t)eSrc[j] * 16 + lg];
            bfacc(acc, u0, eW[j]);
        }
        float4 b0 = ((const float4*)convb)[lg * 2];
        float4 b1 = ((const float4*)convb)[lg * 2 + 1];
        v[0] = fmaxf(acc[0] + b0.x, 0.f); v[1] = fmaxf(acc[1] + b0.y, 0.f);
        v[2] = fmaxf(acc[2] + b0.z, 0.f); v[3] = fmaxf(acc[3] + b0.w, 0.f);
        v[4] = fmaxf(acc[4] + b1.x, 0.f); v[5] = fmaxf(acc[5] + b1.y, 0.f);
        v[6] = fmaxf(acc[6] + b1.z, 0.f); v[7] = fmaxf(acc[7] + b1.w, 0.f);
        ((float4*)out)[(size_t)node * 32 + lg * 2]     = make_float4(v[0], v[1], v[2], v[3]);
        ((float4*)out)[(size_t)node * 32 + lg * 2 + 1] = make_float4(v[4], v[5], v[6], v[7]);
    } else {
#pragma unroll
        for (int k = 0; k < 8; k++) v[k] = 0.f;
    }
    if (STATS) {
        __shared__ float sh[2048];
#pragma unroll
        for (int k = 0; k < 8; k++) sh[t * 8 + k] = v[k];
        __syncthreads();
        if (t < 128) {
            float ts = 0.f, tq = 0.f;
            for (int g = 0; g < 16; g++) {
                float val = sh[g * 128 + t];
                ts += val; tq += val * val;
            }
            atomicAdd(&stats[t], ts);
            atomicAdd(&stats[HF + t], tq);
        }
    }
}

// ---------------- global add pool (batch sorted -> run accumulation) ----------------
__global__ void k_pool(const float* __restrict__ A, const int* __restrict__ batch,
                       float* gpool, int n) {
    int c = threadIdx.x & 127, half = threadIdx.x >> 7;
    int s = blockIdx.x * 64, e = min(s + 64, n);
    int i = s + half;
    if (i < e) {
        float acc = 0.f;
        int cur = batch[i];
        for (; i < e; i += 2) {
            int b = batch[i];
            if (b != cur) {
                atomicAdd(&gpool[cur * HF + c], acc);
                acc = 0.f; cur = b;
            }
            acc += A[(size_t)i * HF + c];
        }
        atomicAdd(&gpool[cur * HF + c], acc);
    }
}

// ---------------- head ----------------
__global__ void k_bnsmall(const float* __restrict__ in, const float* __restrict__ g,
                          const float* __restrict__ b, float* out) {
    int c = threadIdx.x;
    float s = 0.f, q = 0.f;
    for (int r = 0; r < GG; r++) { float v = in[r * HF + c]; s += v; q += v * v; }
    float mean = s / GG;
    float var = q / GG - mean * mean;
    float sc = g[c] * rsqrtf(var + EPS), sh = b[c] - mean * sc;
    for (int r = 0; r < GG; r++) out[r * HF + c] = in[r * HF + c] * sc + sh;
}

__global__ void k_fc(const float* __restrict__ Gbn, const float* __restrict__ Wfc,
                     const float* __restrict__ bfc, float* __restrict__ G2) {
    __shared__ float row[HF];
    int c = threadIdx.x, r = blockIdx.x;
    row[c] = Gbn[r * HF + c];
    __syncthreads();
    float acc = bfc[c];
    for (int k = 0; k < HF; k++) acc += row[k] * Wfc[k * HF + c];
    G2[r * HF + c] = fmaxf(acc, 0.f);
}

__global__ void k_head2(const float* __restrict__ G2, const float* __restrict__ g,
                        const float* __restrict__ b, const float* __restrict__ Wcls,
                        const float* __restrict__ bcls, float* __restrict__ scratch,
                        float* __restrict__ outp) {
    __shared__ float Ls[GG * HF];  // 64 KB
    int c = threadIdx.x;
    float s = 0.f, q = 0.f;
    for (int r = 0; r < GG; r++) { float v = G2[r * HF + c]; s += v; q += v * v; }
    float mean = s / GG;
    float var = q / GG - mean * mean;
    float sc = g[c] * rsqrtf(var + EPS), sh = b[c] - mean * sc;
    for (int r = 0; r < GG; r++) Ls[r * HF + c] = G2[r * HF + c] * sc + sh;
    __syncthreads();
    for (int o = c; o < GG * CC; o += HF) {
        int r = o / CC, j = o % CC;
        float acc = bcls[j];
        for (int k = 0; k < HF; k++) acc += Ls[r * HF + k] * Wcls[k * CC + j];
        scratch[o] = acc;
    }
    __threadfence_block();
    __syncthreads();
    int r = c;  // 128 threads == GG rows
    float m = -1e30f;
    for (int j = 0; j < CC; j++) m = fmaxf(m, scratch[r * CC + j]);
    float se = 0.f;
    for (int j = 0; j < CC; j++) se += expf(scratch[r * CC + j] - m);
    float ls = logf(se);
    for (int j = 0; j < CC; j++) outp[r * CC + j] = scratch[r * CC + j] - m - ls;
}

extern "C" void kernel_launch(void* const* d_in, const int* in_sizes, int n_in,
                              void* d_out, int out_size, void* d_ws, size_t ws_size,
                              hipStream_t stream) {
    const float* x         = (const float*)d_in[0];
    const int*   ei        = (const int*)d_in[1];
    const int*   batch     = (const int*)d_in[2];
    const float* bn_feat_g = (const float*)d_in[3];
    const float* bn_feat_b = (const float*)d_in[4];
    const float* W_feat    = (const float*)d_in[5];
    const float* conv_bn_g = (const float*)d_in[6];
    const float* conv_bn_b = (const float*)d_in[7];
    const float* conv_W    = (const float*)d_in[8];
    const float* conv_b    = (const float*)d_in[9];
    const float* bn_fc_g   = (const float*)d_in[10];
    const float* bn_fc_b   = (const float*)d_in[11];
    const float* W_fc      = (const float*)d_in[12];
    const float* b_fc      = (const float*)d_in[13];
    const float* bn_hid_g  = (const float*)d_in[14];
    const float* bn_hid_b  = (const float*)d_in[15];
    const float* W_cls     = (const float*)d_in[16];
    const float* b_cls     = (const float*)d_in[17];
    float* outp = (float*)d_out;

    int N = in_sizes[0] / HF;
    int E = in_sizes[1] / 2;

    char* w = (char*)d_ws;
    size_t off = 0;
    auto al = [&](size_t bytes) -> void* {
        off = (off + 255) & ~(size_t)255;
        void* p = w + off;
        off += bytes;
        return p;
    };
    float* A      = (float*)al((size_t)N * HF * 4);
    unsigned short* Bf = (unsigned short*)al((size_t)N * HF * 2);   // bf16 y
    int*   eSrc   = (int*)al((size_t)E * 4);
    float* eWt    = (float*)al((size_t)E * 4);
    float* dis    = (float*)al((size_t)N * 4);
    int*   offsb  = (int*)al((size_t)N * 4);
    int*   cursor = (int*)al((size_t)N * 4);
    float* Wt     = (float*)al(HF * HF * 4);
    float* biasT  = (float*)al(HF * 4);
    float* ss     = (float*)al(2 * HF * 4);
    int*   bsum   = (int*)al(1024);
    int*   bscan  = (int*)al(1024);
    float* Gbn    = (float*)al(GG * HF * 4);
    float* G2     = (float*)al(GG * HF * 4);
    // zeroed region
    size_t z0 = (off + 255) & ~(size_t)255;
    off = z0;
    int*   cs    = (int*)al((size_t)N * 4);
    int*   cd    = (int*)al((size_t)N * 4);
    float* Sx    = (float*)al(2 * HF * 4);
    float* S0    = (float*)al(2 * HF * 4);
    float* S1    = (float*)al(2 * HF * 4);
    float* S2    = (float*)al(2 * HF * 4);
    float* gpool = (float*)al(GG * HF * 4);
    size_t zbytes = off - z0;
    hipMemsetAsync(w + z0, 0, zbytes, stream);

    int nbE = (E + 255) / 256;
    int nbN = (N + 255) / 256;

    // graph build
    k_count<<<nbE, 256, 0, stream>>>(ei, E, cs, cd);
    k_dis<<<nbN, 256, 0, stream>>>(cs, dis, N);
    k_scan1<<<nbN, 256, 0, stream>>>(cd, offsb, bsum, N);
    k_scan2<<<1, 256, 0, stream>>>(bsum, bscan, nbN);
    k_scan3<<<nbN, 256, 0, stream>>>(offsb, bscan, cursor, N);
    k_fill<<<nbE, 256, 0, stream>>>(ei, E, dis, cursor, eSrc, eWt);

    // BN(x) stats
    k_colstats<<<400, 256, 0, stream>>>(x, Sx, N);

    // feat layer: h0 = relu(bn(x) @ W_feat), fused stats -> S0
    k_scaleshift<<<1, HF, 0, stream>>>(Sx, bn_feat_g, bn_feat_b, ss, 1.0f / N);
    k_fold<<<HF + 1, HF, 0, stream>>>(W_feat, ss, Wt, biasT);
    k_gemm<1, 1, 0><<<(N + 63) / 64, 256, 0, stream>>>(x, Wt, biasT, A, N, S0);

    float* Sarr[3] = {S0, S1, S2};
    for (int i = 0; i < 3; i++) {
        k_scaleshift<<<1, HF, 0, stream>>>(Sarr[i], conv_bn_g + i * HF, conv_bn_b + i * HF, ss, 1.0f / N);
        k_fold<<<HF + 1, HF, 0, stream>>>(conv_W + (size_t)i * HF * HF, ss, Wt, biasT);
        k_gemm<0, 0, 1><<<(N + 63) / 64, 256, 0, stream>>>(A, Wt, biasT, Bf, N, nullptr);
        if (i < 2)
            k_agg<1><<<(N + 15) / 16, 256, 0, stream>>>(Bf, eSrc, eWt, offsb, cd, dis,
                                                        conv_b + i * HF, A, Sarr[i + 1], N);
        else
            k_agg<0><<<(N + 15) / 16, 256, 0, stream>>>(Bf, eSrc, eWt, offsb, cd, dis,
                                                        conv_b + i * HF, A, nullptr, N);
    }

    // pool + head
    k_pool<<<(N + 63) / 64, 256, 0, stream>>>(A, batch, gpool, N);
    k_bnsmall<<<1, HF, 0, stream>>>(gpool, bn_fc_g, bn_fc_b, Gbn);
    k_fc<<<GG, HF, 0, stream>>>(Gbn, W_fc, b_fc, G2);
    k_head2<<<1, HF, 0, stream>>>(G2, bn_hid_g, bn_hid_b, W_cls, b_cls, Gbn, outp);
}

// Round 3
// 563.573 us; speedup vs baseline: 2.3153x; 1.5983x over previous
//
#include <hip/hip_runtime.h>
#include <hip/hip_bf16.h>

#define HF 128
#define GG 128
#define CC 10
#define EPS 1e-5f

typedef __attribute__((ext_vector_type(8))) short short8;
typedef __attribute__((ext_vector_type(4))) float f32x4;

__device__ inline unsigned short f2bf(float f) {
    unsigned int u = __float_as_uint(f);
    return (unsigned short)((u + 0x7FFFu + ((u >> 16) & 1u)) >> 16);
}

__device__ inline float bf2f(unsigned short h) {
    return __uint_as_float(((unsigned int)h) << 16);
}

__device__ inline void bfacc(float* acc, uint4 u, float w) {
    acc[0] = fmaf(w, __uint_as_float(u.x << 16), acc[0]);
    acc[1] = fmaf(w, __uint_as_float(u.x & 0xFFFF0000u), acc[1]);
    acc[2] = fmaf(w, __uint_as_float(u.y << 16), acc[2]);
    acc[3] = fmaf(w, __uint_as_float(u.y & 0xFFFF0000u), acc[3]);
    acc[4] = fmaf(w, __uint_as_float(u.z << 16), acc[4]);
    acc[5] = fmaf(w, __uint_as_float(u.z & 0xFFFF0000u), acc[5]);
    acc[6] = fmaf(w, __uint_as_float(u.w << 16), acc[6]);
    acc[7] = fmaf(w, __uint_as_float(u.w & 0xFFFF0000u), acc[7]);
}

// ---------------- graph build ----------------
__global__ void k_count(const int* __restrict__ ei, int E, int* cs, int* cd) {
    int e = blockIdx.x * 256 + threadIdx.x;
    if (e < E) {
        atomicAdd(&cs[ei[e]], 1);        // out-degree (src)
        atomicAdd(&cd[ei[E + e]], 1);    // in-degree (dst) for CSR
    }
}

__global__ void k_dis(const int* __restrict__ cs, float* dis, int n) {
    int i = blockIdx.x * 256 + threadIdx.x;
    if (i < n) dis[i] = rsqrtf((float)(1 + cs[i]));  // deg includes self-loop
}

__global__ void k_scan1(const int* __restrict__ cd, int* offs, int* bsum, int n) {
    __shared__ int sh[256];
    int t = threadIdx.x, i = blockIdx.x * 256 + t;
    int v = (i < n) ? cd[i] : 0;
    sh[t] = v; __syncthreads();
    for (int o = 1; o < 256; o <<= 1) {
        int x = (t >= o) ? sh[t - o] : 0;
        __syncthreads();
        sh[t] += x;
        __syncthreads();
    }
    if (i < n) offs[i] = sh[t] - v;          // exclusive within block
    if (t == 255) bsum[blockIdx.x] = sh[255];
}

__global__ void k_scan2(const int* __restrict__ bsum, int* bscan, int nb) {
    __shared__ int sh[256];
    int t = threadIdx.x;
    int v = (t < nb) ? bsum[t] : 0;
    sh[t] = v; __syncthreads();
    for (int o = 1; o < 256; o <<= 1) {
        int x = (t >= o) ? sh[t - o] : 0;
        __syncthreads();
        sh[t] += x;
        __syncthreads();
    }
    if (t < nb) bscan[t] = sh[t] - v;
}

__global__ void k_scan3(int* offs, const int* __restrict__ bscan, int* cursor, int n) {
    int i = blockIdx.x * 256 + threadIdx.x;
    if (i < n) {
        int v = offs[i] + bscan[blockIdx.x];
        offs[i] = v;
        cursor[i] = v;
    }
}

__global__ void k_fill(const int* __restrict__ ei, int E, const float* __restrict__ dis,
                       int* cursor, int* eSrc, float* eW) {
    int e = blockIdx.x * 256 + threadIdx.x;
    if (e < E) {
        int s = ei[e], d = ei[E + e];
        int p = atomicAdd(&cursor[d], 1);
        eSrc[p] = s;
        eW[p] = dis[s] * dis[d];
    }
}

// ---------------- BN stats over x ----------------
__global__ void k_colstats(const float* __restrict__ X, float* stats, int n) {
    int c = threadIdx.x & 127, rl = threadIdx.x >> 7;
    float s = 0.f, q = 0.f;
    for (int i = blockIdx.x * 2 + rl; i < n; i += gridDim.x * 2) {
        float v = X[(size_t)i * HF + c];
        s += v; q += v * v;
    }
    __shared__ float sh[512];
    sh[threadIdx.x] = s; sh[256 + threadIdx.x] = q;
    __syncthreads();
    if (threadIdx.x < 128) {
        atomicAdd(&stats[c],      sh[threadIdx.x] + sh[threadIdx.x + 128]);
        atomicAdd(&stats[HF + c], sh[256 + threadIdx.x] + sh[256 + threadIdx.x + 128]);
    }
}

// ------- BN fold: Wtb[n][k] = bf16(sc[k]*W[k][n]); biasT[n] = sum_k sh[k]*W[k][n] -------
// grid: 128 blocks (n), 128 threads (k)
__global__ void k_foldbias(const float* __restrict__ stats, float cntInv,
                           const float* __restrict__ g, const float* __restrict__ b,
                           const float* __restrict__ W, unsigned short* __restrict__ Wtb,
                           float* __restrict__ biasT) {
    int n = blockIdx.x, k = threadIdx.x;
    float mean = stats[k] * cntInv;
    float var = stats[HF + k] * cntInv - mean * mean;
    float sc = g[k] * rsqrtf(var + EPS);
    float shf = b[k] - mean * sc;
    float wkn = W[k * HF + n];
    Wtb[n * HF + k] = f2bf(sc * wkn);
    __shared__ float red[128];
    red[k] = shf * wkn;
    __syncthreads();
    for (int o = 64; o > 0; o >>= 1) {
        if (k < o) red[k] += red[k + o];
        __syncthreads();
    }
    if (k == 0) biasT[n] = red[0];
}

// ---------------- MFMA GEMM: out[N x 128] = A[N x 128] @ Wt^T + biasT ----------------
// Wtb is [n][k] row-major bf16 (transposed weight). No LDS: A-frags and B-frags are
// direct 16B global loads in fragment layout (A read once; W is L1/L2-hot).
// 128 threads = 2 waves, 32 rows/wave, 64 rows/block.
template <int XIN, int RELU, int STATS>
__global__ __launch_bounds__(128) void k_mgemm(const void* __restrict__ Ain,
                                               const unsigned short* __restrict__ Wtb,
                                               const float* __restrict__ biasT,
                                               unsigned short* __restrict__ out,
                                               int n, float* stats) {
    int l = threadIdx.x & 63, w = threadIdx.x >> 6;
    int lr = l & 15, lc = l >> 4;         // frag row/col, k-chunk
    int rowbase = blockIdx.x * 64 + w * 32;

    f32x4 acc[2][8];
#pragma unroll
    for (int rt = 0; rt < 2; rt++)
#pragma unroll
        for (int nt = 0; nt < 8; nt++) acc[rt][nt] = (f32x4){0.f, 0.f, 0.f, 0.f};

    union U { uint4 u; short8 s; };

    for (int ks = 0; ks < 4; ks++) {
        short8 af[2];
#pragma unroll
        for (int rt = 0; rt < 2; rt++) {
            int row = rowbase + rt * 16 + lr;
            if (XIN) {
                if (row < n) {
                    const float4* xp = (const float4*)((const float*)Ain + (size_t)row * HF + ks * 32 + lc * 8);
                    float4 v0 = xp[0], v1 = xp[1];
                    short8 a;
                    a[0] = (short)f2bf(v0.x); a[1] = (short)f2bf(v0.y);
                    a[2] = (short)f2bf(v0.z); a[3] = (short)f2bf(v0.w);
                    a[4] = (short)f2bf(v1.x); a[5] = (short)f2bf(v1.y);
                    a[6] = (short)f2bf(v1.z); a[7] = (short)f2bf(v1.w);
                    af[rt] = a;
                } else {
                    af[rt] = (short8){0,0,0,0,0,0,0,0};
                }
            } else {
                if (row < n) {
                    U u;
                    u.u = *(const uint4*)((const unsigned short*)Ain + (size_t)row * HF + ks * 32 + lc * 8);
                    af[rt] = u.s;
                } else {
                    af[rt] = (short8){0,0,0,0,0,0,0,0};
                }
            }
        }
#pragma unroll
        for (int nt = 0; nt < 8; nt++) {
            int rn = nt * 16 + lr;
            U ub;
            ub.u = *(const uint4*)(Wtb + (size_t)rn * HF + ks * 32 + lc * 8);
            acc[0][nt] = __builtin_amdgcn_mfma_f32_16x16x32_bf16(af[0], ub.s, acc[0][nt], 0, 0, 0);
            acc[1][nt] = __builtin_amdgcn_mfma_f32_16x16x32_bf16(af[1], ub.s, acc[1][nt], 0, 0, 0);
        }
    }

    // epilogue: D layout col = lane&15 (lr), row = (lane>>4)*4 + r (lc*4+r)
    float s[8], q[8];
#pragma unroll
    for (int nt = 0; nt < 8; nt++) { s[nt] = 0.f; q[nt] = 0.f; }
#pragma unroll
    for (int rt = 0; rt < 2; rt++) {
#pragma unroll
        for (int nt = 0; nt < 8; nt++) {
            float bias = biasT[nt * 16 + lr];
#pragma unroll
            for (int r = 0; r < 4; r++) {
                int row = rowbase + rt * 16 + lc * 4 + r;
                if (row < n) {
                    float v = acc[rt][nt][r] + bias;
                    if (RELU) v = fmaxf(v, 0.f);
                    out[(size_t)row * HF + nt * 16 + lr] = f2bf(v);
                    if (STATS) { s[nt] += v; q[nt] += v * v; }
                }
            }
        }
    }
    if (STATS) {
#pragma unroll
        for (int nt = 0; nt < 8; nt++) {
            s[nt] += __shfl_xor(s[nt], 16);
            q[nt] += __shfl_xor(q[nt], 16);
            s[nt] += __shfl_xor(s[nt], 32);
            q[nt] += __shfl_xor(q[nt], 32);
        }
        if (lc == 0) {
#pragma unroll
            for (int nt = 0; nt < 8; nt++) {
                atomicAdd(&stats[nt * 16 + lr], s[nt]);
                atomicAdd(&stats[HF + nt * 16 + lr], q[nt]);
            }
        }
    }
}

// ------- aggregation: out[i] = relu(dis2*y[i] + sum_e w*y[src] + conv_b), y bf16 -> out bf16 -------
template <int STATS>
__global__ __launch_bounds__(256) void k_agg(const unsigned short* __restrict__ B,
                                             const int* __restrict__ eSrc,
                                             const float* __restrict__ eW,
                                             const int* __restrict__ offs,
                                             const int* __restrict__ cnt,
                                             const float* __restrict__ dis,
                                             const float* __restrict__ convb,
                                             unsigned short* __restrict__ out,
                                             float* stats, int n) {
    int t = threadIdx.x;
    int lg = t & 15;
    int node = blockIdx.x * 16 + (t >> 4);
    const uint4* Bv = (const uint4*)B;
    float acc[8] = {0.f, 0.f, 0.f, 0.f, 0.f, 0.f, 0.f, 0.f};
    float v[8];
    if (node < n) {
        float d = dis[node];
        uint4 us = Bv[(size_t)node * 16 + lg];
        bfacc(acc, us, d * d);
        int j = offs[node], e0 = j + cnt[node];
        for (; j + 4 <= e0; j += 4) {
            int i0 = eSrc[j], i1 = eSrc[j + 1], i2 = eSrc[j + 2], i3 = eSrc[j + 3];
            float w0 = eW[j], w1 = eW[j + 1], w2 = eW[j + 2], w3 = eW[j + 3];
            uint4 u0 = Bv[(size_t)i0 * 16 + lg];
            uint4 u1 = Bv[(size_t)i1 * 16 + lg];
            uint4 u2 = Bv[(size_t)i2 * 16 + lg];
            uint4 u3 = Bv[(size_t)i3 * 16 + lg];
            bfacc(acc, u0, w0); bfacc(acc, u1, w1);
            bfacc(acc, u2, w2); bfacc(acc, u3, w3);
        }
        for (; j < e0; j++) {
            uint4 u0 = Bv[(size_t)eSrc[j] * 16 + lg];
            bfacc(acc, u0, eW[j]);
        }
        float4 b0 = ((const float4*)convb)[lg * 2];
        float4 b1 = ((const float4*)convb)[lg * 2 + 1];
        v[0] = fmaxf(acc[0] + b0.x, 0.f); v[1] = fmaxf(acc[1] + b0.y, 0.f);
        v[2] = fmaxf(acc[2] + b0.z, 0.f); v[3] = fmaxf(acc[3] + b0.w, 0.f);
        v[4] = fmaxf(acc[4] + b1.x, 0.f); v[5] = fmaxf(acc[5] + b1.y, 0.f);
        v[6] = fmaxf(acc[6] + b1.z, 0.f); v[7] = fmaxf(acc[7] + b1.w, 0.f);
        uint4 o;
        o.x = (unsigned int)f2bf(v[0]) | ((unsigned int)f2bf(v[1]) << 16);
        o.y = (unsigned int)f2bf(v[2]) | ((unsigned int)f2bf(v[3]) << 16);
        o.z = (unsigned int)f2bf(v[4]) | ((unsigned int)f2bf(v[5]) << 16);
        o.w = (unsigned int)f2bf(v[6]) | ((unsigned int)f2bf(v[7]) << 16);
        ((uint4*)out)[(size_t)node * 16 + lg] = o;
    } else {
#pragma unroll
        for (int k = 0; k < 8; k++) v[k] = 0.f;
    }
    if (STATS) {
        __shared__ float sh[2048];
#pragma unroll
        for (int k = 0; k < 8; k++) sh[t * 8 + k] = v[k];
        __syncthreads();
        if (t < 128) {
            float ts = 0.f, tq = 0.f;
            for (int g = 0; g < 16; g++) {
                float val = sh[g * 128 + t];
                ts += val; tq += val * val;
            }
            atomicAdd(&stats[t], ts);
            atomicAdd(&stats[HF + t], tq);
        }
    }
}

// ---------------- global add pool (batch sorted -> run accumulation), A bf16 ----------------
__global__ void k_pool(const unsigned short* __restrict__ A, const int* __restrict__ batch,
                       float* gpool, int n) {
    int c = threadIdx.x & 127, half = threadIdx.x >> 7;
    int s = blockIdx.x * 64, e = min(s + 64, n);
    int i = s + half;
    if (i < e) {
        float acc = 0.f;
        int cur = batch[i];
        for (; i < e; i += 2) {
            int b = batch[i];
            if (b != cur) {
                atomicAdd(&gpool[cur * HF + c], acc);
                acc = 0.f; cur = b;
            }
            acc += bf2f(A[(size_t)i * HF + c]);
        }
        atomicAdd(&gpool[cur * HF + c], acc);
    }
}

// ---------------- head ----------------
__global__ void k_bnsmall(const float* __restrict__ in, const float* __restrict__ g,
                          const float* __restrict__ b, float* out) {
    int c = threadIdx.x;
    float s = 0.f, q = 0.f;
    for (int r = 0; r < GG; r++) { float v = in[r * HF + c]; s += v; q += v * v; }
    float mean = s / GG;
    float var = q / GG - mean * mean;
    float sc = g[c] * rsqrtf(var + EPS), sh = b[c] - mean * sc;
    for (int r = 0; r < GG; r++) out[r * HF + c] = in[r * HF + c] * sc + sh;
}

__global__ void k_fc(const float* __restrict__ Gbn, const float* __restrict__ Wfc,
                     const float* __restrict__ bfc, float* __restrict__ G2) {
    __shared__ float row[HF];
    int c = threadIdx.x, r = blockIdx.x;
    row[c] = Gbn[r * HF + c];
    __syncthreads();
    float acc = bfc[c];
    for (int k = 0; k < HF; k++) acc += row[k] * Wfc[k * HF + c];
    G2[r * HF + c] = fmaxf(acc, 0.f);
}

__global__ void k_head2(const float* __restrict__ G2, const float* __restrict__ g,
                        const float* __restrict__ b, const float* __restrict__ Wcls,
                        const float* __restrict__ bcls, float* __restrict__ scratch,
                        float* __restrict__ outp) {
    __shared__ float Ls[GG * HF];  // 64 KB
    int c = threadIdx.x;
    float s = 0.f, q = 0.f;
    for (int r = 0; r < GG; r++) { float v = G2[r * HF + c]; s += v; q += v * v; }
    float mean = s / GG;
    float var = q / GG - mean * mean;
    float sc = g[c] * rsqrtf(var + EPS), sh = b[c] - mean * sc;
    for (int r = 0; r < GG; r++) Ls[r * HF + c] = G2[r * HF + c] * sc + sh;
    __syncthreads();
    for (int o = c; o < GG * CC; o += HF) {
        int r = o / CC, j = o % CC;
        float acc = bcls[j];
        for (int k = 0; k < HF; k++) acc += Ls[r * HF + k] * Wcls[k * CC + j];
        scratch[o] = acc;
    }
    __threadfence_block();
    __syncthreads();
    int r = c;  // 128 threads == GG rows
    float m = -1e30f;
    for (int j = 0; j < CC; j++) m = fmaxf(m, scratch[r * CC + j]);
    float se = 0.f;
    for (int j = 0; j < CC; j++) se += expf(scratch[r * CC + j] - m);
    float ls = logf(se);
    for (int j = 0; j < CC; j++) outp[r * CC + j] = scratch[r * CC + j] - m - ls;
}

extern "C" void kernel_launch(void* const* d_in, const int* in_sizes, int n_in,
                              void* d_out, int out_size, void* d_ws, size_t ws_size,
                              hipStream_t stream) {
    const float* x         = (const float*)d_in[0];
    const int*   ei        = (const int*)d_in[1];
    const int*   batch     = (const int*)d_in[2];
    const float* bn_feat_g = (const float*)d_in[3];
    const float* bn_feat_b = (const float*)d_in[4];
    const float* W_feat    = (const float*)d_in[5];
    const float* conv_bn_g = (const float*)d_in[6];
    const float* conv_bn_b = (const float*)d_in[7];
    const float* conv_W    = (const float*)d_in[8];
    const float* conv_b    = (const float*)d_in[9];
    const float* bn_fc_g   = (const float*)d_in[10];
    const float* bn_fc_b   = (const float*)d_in[11];
    const float* W_fc      = (const float*)d_in[12];
    const float* b_fc      = (const float*)d_in[13];
    const float* bn_hid_g  = (const float*)d_in[14];
    const float* bn_hid_b  = (const float*)d_in[15];
    const float* W_cls     = (const float*)d_in[16];
    const float* b_cls     = (const float*)d_in[17];
    float* outp = (float*)d_out;

    int N = in_sizes[0] / HF;
    int E = in_sizes[1] / 2;

    char* w = (char*)d_ws;
    size_t off = 0;
    auto al = [&](size_t bytes) -> void* {
        off = (off + 255) & ~(size_t)255;
        void* p = w + off;
        off += bytes;
        return p;
    };
    unsigned short* A  = (unsigned short*)al((size_t)N * HF * 2);   // bf16 node features
    unsigned short* Bf = (unsigned short*)al((size_t)N * HF * 2);   // bf16 y = h@W
    int*   eSrc   = (int*)al((size_t)E * 4);
    float* eWt    = (float*)al((size_t)E * 4);
    float* dis    = (float*)al((size_t)N * 4);
    int*   offsb  = (int*)al((size_t)N * 4);
    int*   cursor = (int*)al((size_t)N * 4);
    unsigned short* Wtb = (unsigned short*)al(HF * HF * 2);         // bf16 W^T folded
    float* biasT  = (float*)al(HF * 4);
    int*   bsum   = (int*)al(1024);
    int*   bscan  = (int*)al(1024);
    float* Gbn    = (float*)al(GG * HF * 4);
    float* G2     = (float*)al(GG * HF * 4);
    // zeroed region
    size_t z0 = (off + 255) & ~(size_t)255;
    off = z0;
    int*   cs    = (int*)al((size_t)N * 4);
    int*   cd    = (int*)al((size_t)N * 4);
    float* Sx    = (float*)al(2 * HF * 4);
    float* S0    = (float*)al(2 * HF * 4);
    float* S1    = (float*)al(2 * HF * 4);
    float* S2    = (float*)al(2 * HF * 4);
    float* gpool = (float*)al(GG * HF * 4);
    size_t zbytes = off - z0;
    hipMemsetAsync(w + z0, 0, zbytes, stream);

    int nbE = (E + 255) / 256;
    int nbN = (N + 255) / 256;

    // graph build
    k_count<<<nbE, 256, 0, stream>>>(ei, E, cs, cd);
    k_dis<<<nbN, 256, 0, stream>>>(cs, dis, N);
    k_scan1<<<nbN, 256, 0, stream>>>(cd, offsb, bsum, N);
    k_scan2<<<1, 256, 0, stream>>>(bsum, bscan, nbN);
    k_scan3<<<nbN, 256, 0, stream>>>(offsb, bscan, cursor, N);
    k_fill<<<nbE, 256, 0, stream>>>(ei, E, dis, cursor, eSrc, eWt);

    // BN(x) stats
    k_colstats<<<400, 256, 0, stream>>>(x, Sx, N);

    int gemmGrid = (N + 63) / 64;

    // feat layer: h0 = relu(bn(x) @ W_feat) -> A (bf16), fused stats -> S0
    k_foldbias<<<HF, HF, 0, stream>>>(Sx, 1.0f / N, bn_feat_g, bn_feat_b, W_feat, Wtb, biasT);
    k_mgemm<1, 1, 1><<<gemmGrid, 128, 0, stream>>>(x, Wtb, biasT, A, N, S0);

    float* Sarr[3] = {S0, S1, S2};
    for (int i = 0; i < 3; i++) {
        k_foldbias<<<HF, HF, 0, stream>>>(Sarr[i], 1.0f / N, conv_bn_g + i * HF, conv_bn_b + i * HF,
                                          conv_W + (size_t)i * HF * HF, Wtb, biasT);
        k_mgemm<0, 0, 0><<<gemmGrid, 128, 0, stream>>>(A, Wtb, biasT, Bf, N, nullptr);
        if (i < 2)
            k_agg<1><<<(N + 15) / 16, 256, 0, stream>>>(Bf, eSrc, eWt, offsb, cd, dis,
                                                        conv_b + i * HF, A, Sarr[i + 1], N);
        else
            k_agg<0><<<(N + 15) / 16, 256, 0, stream>>>(Bf, eSrc, eWt, offsb, cd, dis,
                                                        conv_b + i * HF, A, nullptr, N);
    }

    // pool + head
    k_pool<<<(N + 63) / 64, 256, 0, stream>>>(A, batch, gpool, N);
    k_bnsmall<<<1, HF, 0, stream>>>(gpool, bn_fc_g, bn_fc_b, Gbn);
    k_fc<<<GG, HF, 0, stream>>>(Gbn, W_fc, b_fc, G2);
    k_head2<<<1, HF, 0, stream>>>(G2, bn_hid_g, bn_hid_b, W_cls, b_cls, Gbn, outp);
}

// Round 4
// 540.728 us; speedup vs baseline: 2.4131x; 1.0422x over previous
//
#include <hip/hip_runtime.h>
#include <hip/hip_bf16.h>

#define HF 128
#define GG 128
#define CC 10
#define EPS 1e-5f

typedef __attribute__((ext_vector_type(8))) short short8;
typedef __attribute__((ext_vector_type(4))) float f32x4;

__device__ inline unsigned short f2bf(float f) {
    unsigned int u = __float_as_uint(f);
    return (unsigned short)((u + 0x7FFFu + ((u >> 16) & 1u)) >> 16);
}

__device__ inline float bf2f(unsigned short h) {
    return __uint_as_float(((unsigned int)h) << 16);
}

__device__ inline void bfacc(float* acc, uint4 u, float w) {
    acc[0] = fmaf(w, __uint_as_float(u.x << 16), acc[0]);
    acc[1] = fmaf(w, __uint_as_float(u.x & 0xFFFF0000u), acc[1]);
    acc[2] = fmaf(w, __uint_as_float(u.y << 16), acc[2]);
    acc[3] = fmaf(w, __uint_as_float(u.y & 0xFFFF0000u), acc[3]);
    acc[4] = fmaf(w, __uint_as_float(u.z << 16), acc[4]);
    acc[5] = fmaf(w, __uint_as_float(u.z & 0xFFFF0000u), acc[5]);
    acc[6] = fmaf(w, __uint_as_float(u.w << 16), acc[6]);
    acc[7] = fmaf(w, __uint_as_float(u.w & 0xFFFF0000u), acc[7]);
}

// ---------------- graph build ----------------
__global__ void k_count(const int* __restrict__ ei, int E, int* cs, int* cd) {
    int e = blockIdx.x * 256 + threadIdx.x;
    if (e < E) {
        atomicAdd(&cs[ei[e]], 1);        // out-degree (src)
        atomicAdd(&cd[ei[E + e]], 1);    // in-degree (dst) for CSR
    }
}

// scan over cd (in-degree), plus dis = rsqrt(1+deg_out) fused
__global__ void k_scan1(const int* __restrict__ cd, const int* __restrict__ cs,
                        float* __restrict__ dis, int* offs, int* bsum, int n) {
    __shared__ int sh[256];
    int t = threadIdx.x, i = blockIdx.x * 256 + t;
    if (i < n) dis[i] = rsqrtf((float)(1 + cs[i]));
    int v = (i < n) ? cd[i] : 0;
    sh[t] = v; __syncthreads();
    for (int o = 1; o < 256; o <<= 1) {
        int x = (t >= o) ? sh[t - o] : 0;
        __syncthreads();
        sh[t] += x;
        __syncthreads();
    }
    if (i < n) offs[i] = sh[t] - v;          // exclusive within block
    if (t == 255) bsum[blockIdx.x] = sh[255];
}

__global__ void k_scan2(const int* __restrict__ bsum, int* bscan, int nb) {
    __shared__ int sh[256];
    int t = threadIdx.x;
    int v = (t < nb) ? bsum[t] : 0;
    sh[t] = v; __syncthreads();
    for (int o = 1; o < 256; o <<= 1) {
        int x = (t >= o) ? sh[t - o] : 0;
        __syncthreads();
        sh[t] += x;
        __syncthreads();
    }
    if (t < nb) bscan[t] = sh[t] - v;
}

__global__ void k_scan3(int* offs, const int* __restrict__ bscan, int* cursor, int n) {
    int i = blockIdx.x * 256 + threadIdx.x;
    if (i < n) {
        int v = offs[i] + bscan[blockIdx.x];
        offs[i] = v;
        cursor[i] = v;
    }
}

__global__ void k_fill(const int* __restrict__ ei, int E, const float* __restrict__ dis,
                       int* cursor, int2* __restrict__ epk) {
    int e = blockIdx.x * 256 + threadIdx.x;
    if (e < E) {
        int s = ei[e], d = ei[E + e];
        int p = atomicAdd(&cursor[d], 1);
        epk[p] = make_int2(s, __float_as_int(dis[s] * dis[d]));
    }
}

// ---------------- BN stats over x ----------------
__global__ void k_colstats(const float* __restrict__ X, float* stats, int n) {
    int c = threadIdx.x & 127, rl = threadIdx.x >> 7;
    float s = 0.f, q = 0.f;
    for (int i = blockIdx.x * 2 + rl; i < n; i += gridDim.x * 2) {
        float v = X[(size_t)i * HF + c];
        s += v; q += v * v;
    }
    __shared__ float sh[512];
    sh[threadIdx.x] = s; sh[256 + threadIdx.x] = q;
    __syncthreads();
    if (threadIdx.x < 128) {
        atomicAdd(&stats[c],      sh[threadIdx.x] + sh[threadIdx.x + 128]);
        atomicAdd(&stats[HF + c], sh[256 + threadIdx.x] + sh[256 + threadIdx.x + 128]);
    }
}

// ------- BN fold: Wtb[n][k] = bf16(sc[k]*W[k][n]); biasT[n] = sum_k sh[k]*W[k][n] -------
__global__ void k_foldbias(const float* __restrict__ stats, float cntInv,
                           const float* __restrict__ g, const float* __restrict__ b,
                           const float* __restrict__ W, unsigned short* __restrict__ Wtb,
                           float* __restrict__ biasT) {
    int n = blockIdx.x, k = threadIdx.x;
    float mean = stats[k] * cntInv;
    float var = stats[HF + k] * cntInv - mean * mean;
    float sc = g[k] * rsqrtf(var + EPS);
    float shf = b[k] - mean * sc;
    float wkn = W[k * HF + n];
    Wtb[n * HF + k] = f2bf(sc * wkn);
    __shared__ float red[128];
    red[k] = shf * wkn;
    __syncthreads();
    for (int o = 64; o > 0; o >>= 1) {
        if (k < o) red[k] += red[k + o];
        __syncthreads();
    }
    if (k == 0) biasT[n] = red[0];
}

// ---------------- MFMA GEMM: out[N x 128] = A[N x 128] @ Wt^T + biasT ----------------
template <int XIN, int RELU, int STATS>
__global__ __launch_bounds__(128) void k_mgemm(const void* __restrict__ Ain,
                                               const unsigned short* __restrict__ Wtb,
                                               const float* __restrict__ biasT,
                                               unsigned short* __restrict__ out,
                                               int n, float* stats) {
    int l = threadIdx.x & 63, w = threadIdx.x >> 6;
    int lr = l & 15, lc = l >> 4;         // frag row/col, k-chunk
    int rowbase = blockIdx.x * 64 + w * 32;

    f32x4 acc[2][8];
#pragma unroll
    for (int rt = 0; rt < 2; rt++)
#pragma unroll
        for (int nt = 0; nt < 8; nt++) acc[rt][nt] = (f32x4){0.f, 0.f, 0.f, 0.f};

    union U { uint4 u; short8 s; };

    for (int ks = 0; ks < 4; ks++) {
        short8 af[2];
#pragma unroll
        for (int rt = 0; rt < 2; rt++) {
            int row = rowbase + rt * 16 + lr;
            if (XIN) {
                if (row < n) {
                    const float4* xp = (const float4*)((const float*)Ain + (size_t)row * HF + ks * 32 + lc * 8);
                    float4 v0 = xp[0], v1 = xp[1];
                    short8 a;
                    a[0] = (short)f2bf(v0.x); a[1] = (short)f2bf(v0.y);
                    a[2] = (short)f2bf(v0.z); a[3] = (short)f2bf(v0.w);
                    a[4] = (short)f2bf(v1.x); a[5] = (short)f2bf(v1.y);
                    a[6] = (short)f2bf(v1.z); a[7] = (short)f2bf(v1.w);
                    af[rt] = a;
                } else {
                    af[rt] = (short8){0,0,0,0,0,0,0,0};
                }
            } else {
                if (row < n) {
                    U u;
                    u.u = *(const uint4*)((const unsigned short*)Ain + (size_t)row * HF + ks * 32 + lc * 8);
                    af[rt] = u.s;
                } else {
                    af[rt] = (short8){0,0,0,0,0,0,0,0};
                }
            }
        }
#pragma unroll
        for (int nt = 0; nt < 8; nt++) {
            int rn = nt * 16 + lr;
            U ub;
            ub.u = *(const uint4*)(Wtb + (size_t)rn * HF + ks * 32 + lc * 8);
            acc[0][nt] = __builtin_amdgcn_mfma_f32_16x16x32_bf16(af[0], ub.s, acc[0][nt], 0, 0, 0);
            acc[1][nt] = __builtin_amdgcn_mfma_f32_16x16x32_bf16(af[1], ub.s, acc[1][nt], 0, 0, 0);
        }
    }

    // epilogue: D layout col = lane&15 (lr), row = (lane>>4)*4 + r (lc*4+r)
    float s[8], q[8];
#pragma unroll
    for (int nt = 0; nt < 8; nt++) { s[nt] = 0.f; q[nt] = 0.f; }
#pragma unroll
    for (int rt = 0; rt < 2; rt++) {
#pragma unroll
        for (int nt = 0; nt < 8; nt++) {
            float bias = biasT[nt * 16 + lr];
#pragma unroll
            for (int r = 0; r < 4; r++) {
                int row = rowbase + rt * 16 + lc * 4 + r;
                if (row < n) {
                    float v = acc[rt][nt][r] + bias;
                    if (RELU) v = fmaxf(v, 0.f);
                    out[(size_t)row * HF + nt * 16 + lr] = f2bf(v);
                    if (STATS) { s[nt] += v; q[nt] += v * v; }
                }
            }
        }
    }
    if (STATS) {
#pragma unroll
        for (int nt = 0; nt < 8; nt++) {
            s[nt] += __shfl_xor(s[nt], 16);
            q[nt] += __shfl_xor(q[nt], 16);
            s[nt] += __shfl_xor(s[nt], 32);
            q[nt] += __shfl_xor(q[nt], 32);
        }
        if (lc == 0) {
#pragma unroll
            for (int nt = 0; nt < 8; nt++) {
                atomicAdd(&stats[nt * 16 + lr], s[nt]);
                atomicAdd(&stats[HF + nt * 16 + lr], q[nt]);
            }
        }
    }
}

// ------- aggregation: out[i] = relu(dis2*y[i] + sum_e w*y[src] + conv_b) -------
// 16 lanes per node, 8 channels per lane. 8-deep software-pipelined edge chunks:
// prefetch next 8 (src,w) while 8 row-gathers are in flight; pad with (node, w=0).
template <int STATS>
__global__ __launch_bounds__(256) void k_agg(const unsigned short* __restrict__ B,
                                             const int2* __restrict__ epk,
                                             const int* __restrict__ offs,
                                             const int* __restrict__ cnt,
                                             const float* __restrict__ dis,
                                             const float* __restrict__ convb,
                                             unsigned short* __restrict__ out,
                                             float* stats, int n) {
    int t = threadIdx.x;
    int lg = t & 15;
    int node = blockIdx.x * 16 + (t >> 4);
    const uint4* Bv = (const uint4*)B;
    float acc[8] = {0.f, 0.f, 0.f, 0.f, 0.f, 0.f, 0.f, 0.f};
    float v[8];
    if (node < n) {
        float d = dis[node];
        uint4 us = Bv[(size_t)node * 16 + lg];
        bfacc(acc, us, d * d);
        int j = offs[node], e0 = j + cnt[node];
        int2 p[8];
#pragma unroll
        for (int u = 0; u < 8; u++) p[u] = (j + u < e0) ? epk[j + u] : make_int2(node, 0);
        while (j < e0) {
            uint4 g0 = Bv[(size_t)p[0].x * 16 + lg];
            uint4 g1 = Bv[(size_t)p[1].x * 16 + lg];
            uint4 g2 = Bv[(size_t)p[2].x * 16 + lg];
            uint4 g3 = Bv[(size_t)p[3].x * 16 + lg];
            uint4 g4 = Bv[(size_t)p[4].x * 16 + lg];
            uint4 g5 = Bv[(size_t)p[5].x * 16 + lg];
            uint4 g6 = Bv[(size_t)p[6].x * 16 + lg];
            uint4 g7 = Bv[(size_t)p[7].x * 16 + lg];
            int jn = j + 8;
            int2 pn[8];
#pragma unroll
            for (int u = 0; u < 8; u++) pn[u] = (jn + u < e0) ? epk[jn + u] : make_int2(node, 0);
            bfacc(acc, g0, __int_as_float(p[0].y));
            bfacc(acc, g1, __int_as_float(p[1].y));
            bfacc(acc, g2, __int_as_float(p[2].y));
            bfacc(acc, g3, __int_as_float(p[3].y));
            bfacc(acc, g4, __int_as_float(p[4].y));
            bfacc(acc, g5, __int_as_float(p[5].y));
            bfacc(acc, g6, __int_as_float(p[6].y));
            bfacc(acc, g7, __int_as_float(p[7].y));
#pragma unroll
            for (int u = 0; u < 8; u++) p[u] = pn[u];
            j = jn;
        }
        float4 b0 = ((const float4*)convb)[lg * 2];
        float4 b1 = ((const float4*)convb)[lg * 2 + 1];
        v[0] = fmaxf(acc[0] + b0.x, 0.f); v[1] = fmaxf(acc[1] + b0.y, 0.f);
        v[2] = fmaxf(acc[2] + b0.z, 0.f); v[3] = fmaxf(acc[3] + b0.w, 0.f);
        v[4] = fmaxf(acc[4] + b1.x, 0.f); v[5] = fmaxf(acc[5] + b1.y, 0.f);
        v[6] = fmaxf(acc[6] + b1.z, 0.f); v[7] = fmaxf(acc[7] + b1.w, 0.f);
        uint4 o;
        o.x = (unsigned int)f2bf(v[0]) | ((unsigned int)f2bf(v[1]) << 16);
        o.y = (unsigned int)f2bf(v[2]) | ((unsigned int)f2bf(v[3]) << 16);
        o.z = (unsigned int)f2bf(v[4]) | ((unsigned int)f2bf(v[5]) << 16);
        o.w = (unsigned int)f2bf(v[6]) | ((unsigned int)f2bf(v[7]) << 16);
        ((uint4*)out)[(size_t)node * 16 + lg] = o;
    } else {
#pragma unroll
        for (int k = 0; k < 8; k++) v[k] = 0.f;
    }
    if (STATS) {
        __shared__ float sh[2048];
#pragma unroll
        for (int k = 0; k < 8; k++) sh[t * 8 + k] = v[k];
        __syncthreads();
        if (t < 128) {
            float ts = 0.f, tq = 0.f;
            for (int g = 0; g < 16; g++) {
                float val = sh[g * 128 + t];
                ts += val; tq += val * val;
            }
            atomicAdd(&stats[t], ts);
            atomicAdd(&stats[HF + t], tq);
        }
    }
}

// ---------------- global add pool: 4 blocks per graph, binary-searched ranges ----------------
__global__ __launch_bounds__(256) void k_pool(const unsigned short* __restrict__ A,
                                              const int* __restrict__ batch,
                                              float* gpool, int n) {
    int g = blockIdx.x >> 2, part = blockIdx.x & 3;
    int lo, hi;
    {
        int l = 0, r = n;
        while (l < r) { int m = (l + r) >> 1; if (batch[m] < g) l = m + 1; else r = m; }
        lo = l;
    }
    {
        int l = lo, r = n;
        while (l < r) { int m = (l + r) >> 1; if (batch[m] < g + 1) l = m + 1; else r = m; }
        hi = l;
    }
    int cntg = hi - lo;
    if (cntg <= 0) return;
    int per = (cntg + 3) >> 2;
    int s = lo + part * per, e = min(s + per, hi);
    int c2 = threadIdx.x & 63;    // one uint = 2 bf16 channels
    int rl = threadIdx.x >> 6;    // 4 rows in parallel
    float a0 = 0.f, a1 = 0.f;
    for (int i = s + rl; i < e; i += 4) {
        unsigned int u = ((const unsigned int*)(A + (size_t)i * HF))[c2];
        a0 += bf2f((unsigned short)(u & 0xFFFFu));
        a1 += bf2f((unsigned short)(u >> 16));
    }
    __shared__ float sh[512];
    sh[rl * 128 + c2 * 2] = a0;
    sh[rl * 128 + c2 * 2 + 1] = a1;
    __syncthreads();
    if (threadIdx.x < 128 && s < hi) {
        float s4 = sh[threadIdx.x] + sh[128 + threadIdx.x] + sh[256 + threadIdx.x] + sh[384 + threadIdx.x];
        atomicAdd(&gpool[g * HF + threadIdx.x], s4);
    }
}

// ---------------- head ----------------
__global__ void k_bnsmall(const float* __restrict__ in, const float* __restrict__ g,
                          const float* __restrict__ b, float* out) {
    int c = threadIdx.x;
    float s = 0.f, q = 0.f;
    for (int r = 0; r < GG; r++) { float v = in[r * HF + c]; s += v; q += v * v; }
    float mean = s / GG;
    float var = q / GG - mean * mean;
    float sc = g[c] * rsqrtf(var + EPS), sh = b[c] - mean * sc;
    for (int r = 0; r < GG; r++) out[r * HF + c] = in[r * HF + c] * sc + sh;
}

__global__ void k_fc(const float* __restrict__ Gbn, const float* __restrict__ Wfc,
                     const float* __restrict__ bfc, float* __restrict__ G2) {
    __shared__ float row[HF];
    int c = threadIdx.x, r = blockIdx.x;
    row[c] = Gbn[r * HF + c];
    __syncthreads();
    float acc = bfc[c];
    for (int k = 0; k < HF; k++) acc += row[k] * Wfc[k * HF + c];
    G2[r * HF + c] = fmaxf(acc, 0.f);
}

__global__ void k_head2(const float* __restrict__ G2, const float* __restrict__ g,
                        const float* __restrict__ b, const float* __restrict__ Wcls,
                        const float* __restrict__ bcls, float* __restrict__ scratch,
                        float* __restrict__ outp) {
    __shared__ float Ls[GG * HF];  // 64 KB
    int c = threadIdx.x;
    float s = 0.f, q = 0.f;
    for (int r = 0; r < GG; r++) { float v = G2[r * HF + c]; s += v; q += v * v; }
    float mean = s / GG;
    float var = q / GG - mean * mean;
    float sc = g[c] * rsqrtf(var + EPS), sh = b[c] - mean * sc;
    for (int r = 0; r < GG; r++) Ls[r * HF + c] = G2[r * HF + c] * sc + sh;
    __syncthreads();
    for (int o = c; o < GG * CC; o += HF) {
        int r = o / CC, j = o % CC;
        float acc = bcls[j];
        for (int k = 0; k < HF; k++) acc += Ls[r * HF + k] * Wcls[k * CC + j];
        scratch[o] = acc;
    }
    __threadfence_block();
    __syncthreads();
    int r = c;  // 128 threads == GG rows
    float m = -1e30f;
    for (int j = 0; j < CC; j++) m = fmaxf(m, scratch[r * CC + j]);
    float se = 0.f;
    for (int j = 0; j < CC; j++) se += expf(scratch[r * CC + j] - m);
    float ls = logf(se);
    for (int j = 0; j < CC; j++) outp[r * CC + j] = scratch[r * CC + j] - m - ls;
}

extern "C" void kernel_launch(void* const* d_in, const int* in_sizes, int n_in,
                              void* d_out, int out_size, void* d_ws, size_t ws_size,
                              hipStream_t stream) {
    const float* x         = (const float*)d_in[0];
    const int*   ei        = (const int*)d_in[1];
    const int*   batch     = (const int*)d_in[2];
    const float* bn_feat_g = (const float*)d_in[3];
    const float* bn_feat_b = (const float*)d_in[4];
    const float* W_feat    = (const float*)d_in[5];
    const float* conv_bn_g = (const float*)d_in[6];
    const float* conv_bn_b = (const float*)d_in[7];
    const float* conv_W    = (const float*)d_in[8];
    const float* conv_b    = (const float*)d_in[9];
    const float* bn_fc_g   = (const float*)d_in[10];
    const float* bn_fc_b   = (const float*)d_in[11];
    const float* W_fc      = (const float*)d_in[12];
    const float* b_fc      = (const float*)d_in[13];
    const float* bn_hid_g  = (const float*)d_in[14];
    const float* bn_hid_b  = (const float*)d_in[15];
    const float* W_cls     = (const float*)d_in[16];
    const float* b_cls     = (const float*)d_in[17];
    float* outp = (float*)d_out;

    int N = in_sizes[0] / HF;
    int E = in_sizes[1] / 2;

    char* w = (char*)d_ws;
    size_t off = 0;
    auto al = [&](size_t bytes) -> void* {
        off = (off + 255) & ~(size_t)255;
        void* p = w + off;
        off += bytes;
        return p;
    };
    unsigned short* A  = (unsigned short*)al((size_t)N * HF * 2);   // bf16 node features
    unsigned short* Bf = (unsigned short*)al((size_t)N * HF * 2);   // bf16 y = h@W
    int2*  epk    = (int2*)al((size_t)E * 8);                        // packed (src, w)
    float* dis    = (float*)al((size_t)N * 4);
    int*   offsb  = (int*)al((size_t)N * 4);
    int*   cursor = (int*)al((size_t)N * 4);
    unsigned short* Wtb = (unsigned short*)al(HF * HF * 2);         // bf16 W^T folded
    float* biasT  = (float*)al(HF * 4);
    int*   bsum   = (int*)al(1024);
    int*   bscan  = (int*)al(1024);
    float* Gbn    = (float*)al(GG * HF * 4);
    float* G2     = (float*)al(GG * HF * 4);
    // zeroed region
    size_t z0 = (off + 255) & ~(size_t)255;
    off = z0;
    int*   cs    = (int*)al((size_t)N * 4);
    int*   cd    = (int*)al((size_t)N * 4);
    float* Sx    = (float*)al(2 * HF * 4);
    float* S0    = (float*)al(2 * HF * 4);
    float* S1    = (float*)al(2 * HF * 4);
    float* S2    = (float*)al(2 * HF * 4);
    float* gpool = (float*)al(GG * HF * 4);
    size_t zbytes = off - z0;
    hipMemsetAsync(w + z0, 0, zbytes, stream);

    int nbE = (E + 255) / 256;
    int nbN = (N + 255) / 256;

    // graph build
    k_count<<<nbE, 256, 0, stream>>>(ei, E, cs, cd);
    k_scan1<<<nbN, 256, 0, stream>>>(cd, cs, dis, offsb, bsum, N);
    k_scan2<<<1, 256, 0, stream>>>(bsum, bscan, nbN);
    k_scan3<<<nbN, 256, 0, stream>>>(offsb, bscan, cursor, N);
    k_fill<<<nbE, 256, 0, stream>>>(ei, E, dis, cursor, epk);

    // BN(x) stats
    k_colstats<<<400, 256, 0, stream>>>(x, Sx, N);

    int gemmGrid = (N + 63) / 64;

    // feat layer: h0 = relu(bn(x) @ W_feat) -> A (bf16), fused stats -> S0
    k_foldbias<<<HF, HF, 0, stream>>>(Sx, 1.0f / N, bn_feat_g, bn_feat_b, W_feat, Wtb, biasT);
    k_mgemm<1, 1, 1><<<gemmGrid, 128, 0, stream>>>(x, Wtb, biasT, A, N, S0);

    float* Sarr[3] = {S0, S1, S2};
    for (int i = 0; i < 3; i++) {
        k_foldbias<<<HF, HF, 0, stream>>>(Sarr[i], 1.0f / N, conv_bn_g + i * HF, conv_bn_b + i * HF,
                                          conv_W + (size_t)i * HF * HF, Wtb, biasT);
        k_mgemm<0, 0, 0><<<gemmGrid, 128, 0, stream>>>(A, Wtb, biasT, Bf, N, nullptr);
        if (i < 2)
            k_agg<1><<<(N + 15) / 16, 256, 0, stream>>>(Bf, epk, offsb, cd, dis,
                                                        conv_b + i * HF, A, Sarr[i + 1], N);
        else
            k_agg<0><<<(N + 15) / 16, 256, 0, stream>>>(Bf, epk, offsb, cd, dis,
                                                        conv_b + i * HF, A, nullptr, N);
    }

    // pool + head
    k_pool<<<GG * 4, 256, 0, stream>>>(A, batch, gpool, N);
    k_bnsmall<<<1, HF, 0, stream>>>(gpool, bn_fc_g, bn_fc_b, Gbn);
    k_fc<<<GG, HF, 0, stream>>>(Gbn, W_fc, b_fc, G2);
    k_head2<<<1, HF, 0, stream>>>(G2, bn_hid_g, bn_hid_b, W_cls, b_cls, Gbn, outp);
}

// Round 7
// 538.371 us; speedup vs baseline: 2.4237x; 1.0044x over previous
//
#include <hip/hip_runtime.h>
#include <hip/hip_bf16.h>

#define HF 128
#define GG 128
#define CC 10
#define EPS 1e-5f

typedef __attribute__((ext_vector_type(8))) short short8;
typedef __attribute__((ext_vector_type(4))) float f32x4;

__device__ inline unsigned short f2bf(float f) {
    unsigned int u = __float_as_uint(f);
    return (unsigned short)((u + 0x7FFFu + ((u >> 16) & 1u)) >> 16);
}

__device__ inline float bf2f(unsigned short h) {
    return __uint_as_float(((unsigned int)h) << 16);
}

// acc[0..7] += w * sext_int8x8(u)
__device__ inline void i8acc(float* acc, uint2 u, float w) {
    acc[0] = fmaf(w, (float)((int)(u.x << 24) >> 24), acc[0]);
    acc[1] = fmaf(w, (float)((int)(u.x << 16) >> 24), acc[1]);
    acc[2] = fmaf(w, (float)((int)(u.x << 8) >> 24), acc[2]);
    acc[3] = fmaf(w, (float)((int)u.x >> 24), acc[3]);
    acc[4] = fmaf(w, (float)((int)(u.y << 24) >> 24), acc[4]);
    acc[5] = fmaf(w, (float)((int)(u.y << 16) >> 24), acc[5]);
    acc[6] = fmaf(w, (float)((int)(u.y << 8) >> 24), acc[6]);
    acc[7] = fmaf(w, (float)((int)u.y >> 24), acc[7]);
}

__device__ inline unsigned int pk4i8(float a, float b, float c, float d, float inv) {
    int q0 = (int)rintf(a * inv), q1 = (int)rintf(b * inv);
    int q2 = (int)rintf(c * inv), q3 = (int)rintf(d * inv);
    return (unsigned int)(q0 & 255) | ((unsigned int)(q1 & 255) << 8) |
           ((unsigned int)(q2 & 255) << 16) | ((unsigned int)(q3 & 255) << 24);
}

// ---------------- graph build ----------------
__global__ void k_count(const int* __restrict__ ei, int E, int* cs, int* cd) {
    int e = blockIdx.x * 256 + threadIdx.x;
    if (e < E) {
        atomicAdd(&cs[ei[e]], 1);
        atomicAdd(&cd[ei[E + e]], 1);
    }
}

__global__ void k_scan1(const int* __restrict__ cd, const int* __restrict__ cs,
                        float* __restrict__ dis, int* offs, int* bsum, int n) {
    __shared__ int sh[256];
    int t = threadIdx.x, i = blockIdx.x * 256 + t;
    if (i < n) dis[i] = rsqrtf((float)(1 + cs[i]));
    int v = (i < n) ? cd[i] : 0;
    sh[t] = v; __syncthreads();
    for (int o = 1; o < 256; o <<= 1) {
        int x = (t >= o) ? sh[t - o] : 0;
        __syncthreads();
        sh[t] += x;
        __syncthreads();
    }
    if (i < n) offs[i] = sh[t] - v;
    if (t == 255) bsum[blockIdx.x] = sh[255];
}

__global__ void k_scan2(const int* __restrict__ bsum, int* bscan, int nb) {
    __shared__ int sh[256];
    int t = threadIdx.x;
    int v = (t < nb) ? bsum[t] : 0;
    sh[t] = v; __syncthreads();
    for (int o = 1; o < 256; o <<= 1) {
        int x = (t >= o) ? sh[t - o] : 0;
        __syncthreads();
        sh[t] += x;
        __syncthreads();
    }
    if (t < nb) bscan[t] = sh[t] - v;
}

__global__ void k_scan3(int* offs, const int* __restrict__ bscan, int* cursor, int n) {
    int i = blockIdx.x * 256 + threadIdx.x;
    if (i < n) {
        int v = offs[i] + bscan[blockIdx.x];
        offs[i] = v;
        cursor[i] = v;
    }
}

__global__ void k_fill(const int* __restrict__ ei, int E, const float* __restrict__ dis,
                       int* cursor, int2* __restrict__ epk) {
    int e = blockIdx.x * 256 + threadIdx.x;
    if (e < E) {
        int s = ei[e], d = ei[E + e];
        int p = atomicAdd(&cursor[d], 1);
        epk[p] = make_int2(s, __float_as_int(dis[s] * dis[d]));
    }
}

// ---------------- BN stats over x ----------------
__global__ void k_colstats(const float* __restrict__ X, float* stats, int n) {
    int c = threadIdx.x & 127, rl = threadIdx.x >> 7;
    float s = 0.f, q = 0.f;
    for (int i = blockIdx.x * 2 + rl; i < n; i += gridDim.x * 2) {
        float v = X[(size_t)i * HF + c];
        s += v; q += v * v;
    }
    __shared__ float sh[512];
    sh[threadIdx.x] = s; sh[256 + threadIdx.x] = q;
    __syncthreads();
    if (threadIdx.x < 128) {
        atomicAdd(&stats[c],      sh[threadIdx.x] + sh[threadIdx.x + 128]);
        atomicAdd(&stats[HF + c], sh[256 + threadIdx.x] + sh[256 + threadIdx.x + 128]);
    }
}

// ------- BN fold -------
__global__ void k_foldbias(const float* __restrict__ stats, float cntInv,
                           const float* __restrict__ g, const float* __restrict__ b,
                           const float* __restrict__ W, unsigned short* __restrict__ Wtb,
                           float* __restrict__ biasT) {
    int n = blockIdx.x, k = threadIdx.x;
    float mean = stats[k] * cntInv;
    float var = stats[HF + k] * cntInv - mean * mean;
    float sc = g[k] * rsqrtf(var + EPS);
    float shf = b[k] - mean * sc;
    float wkn = W[k * HF + n];
    Wtb[n * HF + k] = f2bf(sc * wkn);
    __shared__ float red[128];
    red[k] = shf * wkn;
    __syncthreads();
    for (int o = 64; o > 0; o >>= 1) {
        if (k < o) red[k] += red[k + o];
        __syncthreads();
    }
    if (k == 0) biasT[n] = red[0];
}

// ---------------- MFMA GEMM: out = A @ Wt^T + biasT ----------------
// 256 threads = 4 waves, 32 rows/wave, 128 rows/block.
// OUTQ=1: int8 rows (128B) + per-row scale into rowscl. OUTQ=0: bf16 rows (256B).
template <int XIN, int RELU, int STATS, int OUTQ>
__global__ __launch_bounds__(256) void k_mgemm(const void* __restrict__ Ain,
                                               const unsigned short* __restrict__ Wtb,
                                               const float* __restrict__ biasT,
                                               void* __restrict__ outv,
                                               float* __restrict__ rowscl,
                                               int n, float* stats) {
    __shared__ float Ls[4][16 * 128];   // 32 KB: per-wave transpose tile
    __shared__ float bsh[128];
    int l = threadIdx.x & 63, w = threadIdx.x >> 6;
    int lr = l & 15, lc = l >> 4;
    int rowbase = blockIdx.x * 128 + w * 32;
    if (threadIdx.x < 128) bsh[threadIdx.x] = biasT[threadIdx.x];

    f32x4 acc[2][8];
#pragma unroll
    for (int rt = 0; rt < 2; rt++)
#pragma unroll
        for (int nt = 0; nt < 8; nt++) acc[rt][nt] = (f32x4){0.f, 0.f, 0.f, 0.f};

    union U { uint4 u; short8 s; };

    for (int ks = 0; ks < 4; ks++) {
        short8 af[2];
#pragma unroll
        for (int rt = 0; rt < 2; rt++) {
            int row = rowbase + rt * 16 + lr;
            if (XIN) {
                if (row < n) {
                    const float4* xp = (const float4*)((const float*)Ain + (size_t)row * HF + ks * 32 + lc * 8);
                    float4 v0 = xp[0], v1 = xp[1];
                    short8 a;
                    a[0] = (short)f2bf(v0.x); a[1] = (short)f2bf(v0.y);
                    a[2] = (short)f2bf(v0.z); a[3] = (short)f2bf(v0.w);
                    a[4] = (short)f2bf(v1.x); a[5] = (short)f2bf(v1.y);
                    a[6] = (short)f2bf(v1.z); a[7] = (short)f2bf(v1.w);
                    af[rt] = a;
                } else af[rt] = (short8){0,0,0,0,0,0,0,0};
            } else {
                if (row < n) {
                    U u;
                    u.u = *(const uint4*)((const unsigned short*)Ain + (size_t)row * HF + ks * 32 + lc * 8);
                    af[rt] = u.s;
                } else af[rt] = (short8){0,0,0,0,0,0,0,0};
            }
        }
#pragma unroll
        for (int nt = 0; nt < 8; nt++) {
            U ub;
            ub.u = *(const uint4*)(Wtb + (size_t)(nt * 16 + lr) * HF + ks * 32 + lc * 8);
            acc[0][nt] = __builtin_amdgcn_mfma_f32_16x16x32_bf16(af[0], ub.s, acc[0][nt], 0, 0, 0);
            acc[1][nt] = __builtin_amdgcn_mfma_f32_16x16x32_bf16(af[1], ub.s, acc[1][nt], 0, 0, 0);
        }
    }
    __syncthreads();   // bsh ready

    if (STATS) {
        float s[8], q[8];
#pragma unroll
        for (int nt = 0; nt < 8; nt++) { s[nt] = 0.f; q[nt] = 0.f; }
#pragma unroll
        for (int rt = 0; rt < 2; rt++) {
#pragma unroll
            for (int nt = 0; nt < 8; nt++) {
                float bias = bsh[nt * 16 + lr];
#pragma unroll
                for (int r = 0; r < 4; r++) {
                    int row = rowbase + rt * 16 + lc * 4 + r;
                    if (row < n) {
                        float v = acc[rt][nt][r] + bias;
                        if (RELU) v = fmaxf(v, 0.f);
                        s[nt] += v; q[nt] += v * v;
                    }
                }
            }
        }
#pragma unroll
        for (int nt = 0; nt < 8; nt++) {
            s[nt] += __shfl_xor(s[nt], 16);
            q[nt] += __shfl_xor(q[nt], 16);
            s[nt] += __shfl_xor(s[nt], 32);
            q[nt] += __shfl_xor(q[nt], 32);
        }
        if (lc == 0) {
#pragma unroll
            for (int nt = 0; nt < 8; nt++) {
                atomicAdd(&stats[nt * 16 + lr], s[nt]);
                atomicAdd(&stats[HF + nt * 16 + lr], q[nt]);
            }
        }
    }

    // transpose via LDS, coalesced stores
    float* LsW = Ls[w];
    for (int rt = 0; rt < 2; rt++) {
#pragma unroll
        for (int nt = 0; nt < 8; nt++)
#pragma unroll
            for (int r = 0; r < 4; r++)
                LsW[(lc * 4 + r) * 128 + nt * 16 + lr] = acc[rt][nt][r];
        __syncthreads();
        int r16 = l >> 2, cc = (l & 3) * 32;
        int row = rowbase + rt * 16 + r16;
        if (row < n) {
            float v[32];
#pragma unroll
            for (int j = 0; j < 32; j++) {
                float tv = LsW[r16 * 128 + cc + j] + bsh[cc + j];
                if (RELU) tv = fmaxf(tv, 0.f);
                v[j] = tv;
            }
            if (OUTQ) {
                float m = 0.f;
#pragma unroll
                for (int j = 0; j < 32; j++) m = fmaxf(m, fabsf(v[j]));
                m = fmaxf(m, __shfl_xor(m, 1));
                m = fmaxf(m, __shfl_xor(m, 2));
                float inv = (m > 1e-20f) ? 127.f / m : 0.f;
                unsigned int o[8];
#pragma unroll
                for (int j = 0; j < 8; j++)
                    o[j] = pk4i8(v[4 * j], v[4 * j + 1], v[4 * j + 2], v[4 * j + 3], inv);
                uint4* dst = (uint4*)((unsigned char*)outv + (size_t)row * 128 + cc);
                dst[0] = make_uint4(o[0], o[1], o[2], o[3]);
                dst[1] = make_uint4(o[4], o[5], o[6], o[7]);
                if ((l & 3) == 0) rowscl[row] = m * (1.f / 127.f);
            } else {
                unsigned int o[16];
#pragma unroll
                for (int j = 0; j < 16; j++)
                    o[j] = (unsigned int)f2bf(v[2 * j]) | ((unsigned int)f2bf(v[2 * j + 1]) << 16);
                uint4* dst = (uint4*)((unsigned short*)outv + (size_t)row * HF + cc);
                dst[0] = make_uint4(o[0], o[1], o[2], o[3]);
                dst[1] = make_uint4(o[4], o[5], o[6], o[7]);
                dst[2] = make_uint4(o[8], o[9], o[10], o[11]);
                dst[3] = make_uint4(o[12], o[13], o[14], o[15]);
            }
        }
        __syncthreads();
    }
}

// ------- aggregation: out[i] = relu(scl_i*dis2*y[i] + sum_e w*scl_s*y[src] + conv_b) -------
// y rows are int8 (128B) + per-row scale rsc[]. 16 lanes/node (uint2 = 8 ch), 16 nodes/block,
// 8-deep pipelined edge chunks with scale prefetch.
template <int STATS>
__global__ __launch_bounds__(256) void k_agg(const unsigned char* __restrict__ B,
                                             const float* __restrict__ rsc,
                                             const int2* __restrict__ epk,
                                             const int* __restrict__ offs,
                                             const int* __restrict__ cnt,
                                             const float* __restrict__ dis,
                                             const float* __restrict__ convb,
                                             unsigned short* __restrict__ out,
                                             float* stats, int n) {
    int t = threadIdx.x;
    int lg = t & 15;
    int node = blockIdx.x * 16 + (t >> 4);
    const uint2* Bv = (const uint2*)B;
    float acc[8] = {0.f, 0.f, 0.f, 0.f, 0.f, 0.f, 0.f, 0.f};
    float v[8];
    if (node < n) {
        float d = dis[node];
        i8acc(acc, Bv[(size_t)node * 16 + lg], d * d * rsc[node]);
        int j = offs[node], e0 = j + cnt[node];
        int2 p[8]; float sp[8];
#pragma unroll
        for (int u = 0; u < 8; u++) p[u] = (j + u < e0) ? epk[j + u] : make_int2(node, 0);
#pragma unroll
        for (int u = 0; u < 8; u++) sp[u] = rsc[p[u].x];
        while (j < e0) {
            uint2 g0 = Bv[(size_t)p[0].x * 16 + lg];
            uint2 g1 = Bv[(size_t)p[1].x * 16 + lg];
            uint2 g2 = Bv[(size_t)p[2].x * 16 + lg];
            uint2 g3 = Bv[(size_t)p[3].x * 16 + lg];
            uint2 g4 = Bv[(size_t)p[4].x * 16 + lg];
            uint2 g5 = Bv[(size_t)p[5].x * 16 + lg];
            uint2 g6 = Bv[(size_t)p[6].x * 16 + lg];
            uint2 g7 = Bv[(size_t)p[7].x * 16 + lg];
            int jn = j + 8;
            int2 pn[8]; float spn[8];
#pragma unroll
            for (int u = 0; u < 8; u++) pn[u] = (jn + u < e0) ? epk[jn + u] : make_int2(node, 0);
#pragma unroll
            for (int u = 0; u < 8; u++) spn[u] = rsc[pn[u].x];
            i8acc(acc, g0, __int_as_float(p[0].y) * sp[0]);
            i8acc(acc, g1, __int_as_float(p[1].y) * sp[1]);
            i8acc(acc, g2, __int_as_float(p[2].y) * sp[2]);
            i8acc(acc, g3, __int_as_float(p[3].y) * sp[3]);
            i8acc(acc, g4, __int_as_float(p[4].y) * sp[4]);
            i8acc(acc, g5, __int_as_float(p[5].y) * sp[5]);
            i8acc(acc, g6, __int_as_float(p[6].y) * sp[6]);
            i8acc(acc, g7, __int_as_float(p[7].y) * sp[7]);
#pragma unroll
            for (int u = 0; u < 8; u++) { p[u] = pn[u]; sp[u] = spn[u]; }
            j = jn;
        }
        float4 b0 = ((const float4*)convb)[lg * 2];
        float4 b1 = ((const float4*)convb)[lg * 2 + 1];
        v[0] = fmaxf(acc[0] + b0.x, 0.f); v[1] = fmaxf(acc[1] + b0.y, 0.f);
        v[2] = fmaxf(acc[2] + b0.z, 0.f); v[3] = fmaxf(acc[3] + b0.w, 0.f);
        v[4] = fmaxf(acc[4] + b1.x, 0.f); v[5] = fmaxf(acc[5] + b1.y, 0.f);
        v[6] = fmaxf(acc[6] + b1.z, 0.f); v[7] = fmaxf(acc[7] + b1.w, 0.f);
        uint4 o;
        o.x = (unsigned int)f2bf(v[0]) | ((unsigned int)f2bf(v[1]) << 16);
        o.y = (unsigned int)f2bf(v[2]) | ((unsigned int)f2bf(v[3]) << 16);
        o.z = (unsigned int)f2bf(v[4]) | ((unsigned int)f2bf(v[5]) << 16);
        o.w = (unsigned int)f2bf(v[6]) | ((unsigned int)f2bf(v[7]) << 16);
        ((uint4*)out)[(size_t)node * 16 + lg] = o;
    } else {
#pragma unroll
        for (int k = 0; k < 8; k++) v[k] = 0.f;
    }
    if (STATS) {
        __shared__ float sh[2048];
#pragma unroll
        for (int k = 0; k < 8; k++) sh[t * 8 + k] = v[k];
        __syncthreads();
        if (t < 128) {
            float ts = 0.f, tq = 0.f;
            for (int g = 0; g < 16; g++) {
                float val = sh[g * 128 + t];
                ts += val; tq += val * val;
            }
            atomicAdd(&stats[t], ts);
            atomicAdd(&stats[HF + t], tq);
        }
    }
}

// ---------------- global add pool ----------------
__global__ __launch_bounds__(256) void k_pool(const unsigned short* __restrict__ A,
                                              const int* __restrict__ batch,
                                              float* gpool, int n) {
    int g = blockIdx.x >> 2, part = blockIdx.x & 3;
    int lo, hi;
    {
        int l = 0, r = n;
        while (l < r) { int m = (l + r) >> 1; if (batch[m] < g) l = m + 1; else r = m; }
        lo = l;
    }
    {
        int l = lo, r = n;
        while (l < r) { int m = (l + r) >> 1; if (batch[m] < g + 1) l = m + 1; else r = m; }
        hi = l;
    }
    int cntg = hi - lo;
    if (cntg <= 0) return;
    int per = (cntg + 3) >> 2;
    int s = lo + part * per, e = min(s + per, hi);
    int c2 = threadIdx.x & 63;
    int rl = threadIdx.x >> 6;
    float a0 = 0.f, a1 = 0.f;
    for (int i = s + rl; i < e; i += 4) {
        unsigned int u = ((const unsigned int*)(A + (size_t)i * HF))[c2];
        a0 += bf2f((unsigned short)(u & 0xFFFFu));
        a1 += bf2f((unsigned short)(u >> 16));
    }
    __shared__ float sh[512];
    sh[rl * 128 + c2 * 2] = a0;
    sh[rl * 128 + c2 * 2 + 1] = a1;
    __syncthreads();
    if (threadIdx.x < 128 && s < hi) {
        float s4 = sh[threadIdx.x] + sh[128 + threadIdx.x] + sh[256 + threadIdx.x] + sh[384 + threadIdx.x];
        atomicAdd(&gpool[g * HF + threadIdx.x], s4);
    }
}

// ---------------- head ----------------
__global__ void k_bnsmall(const float* __restrict__ in, const float* __restrict__ g,
                          const float* __restrict__ b, float* out) {
    int c = threadIdx.x;
    float s = 0.f, q = 0.f;
    for (int r = 0; r < GG; r++) { float v = in[r * HF + c]; s += v; q += v * v; }
    float mean = s / GG;
    float var = q / GG - mean * mean;
    float sc = g[c] * rsqrtf(var + EPS), sh = b[c] - mean * sc;
    for (int r = 0; r < GG; r++) out[r * HF + c] = in[r * HF + c] * sc + sh;
}

__global__ void k_fc(const float* __restrict__ Gbn, const float* __restrict__ Wfc,
                     const float* __restrict__ bfc, float* __restrict__ G2) {
    __shared__ float row[HF];
    int c = threadIdx.x, r = blockIdx.x;
    row[c] = Gbn[r * HF + c];
    __syncthreads();
    float acc = bfc[c];
    for (int k = 0; k < HF; k++) acc += row[k] * Wfc[k * HF + c];
    G2[r * HF + c] = fmaxf(acc, 0.f);
}

__global__ void k_head2(const float* __restrict__ G2, const float* __restrict__ g,
                        const float* __restrict__ b, const float* __restrict__ Wcls,
                        const float* __restrict__ bcls, float* __restrict__ scratch,
                        float* __restrict__ outp) {
    __shared__ float Ls[GG * HF];
    int c = threadIdx.x;
    float s = 0.f, q = 0.f;
    for (int r = 0; r < GG; r++) { float v = G2[r * HF + c]; s += v; q += v * v; }
    float mean = s / GG;
    float var = q / GG - mean * mean;
    float sc = g[c] * rsqrtf(var + EPS), sh = b[c] - mean * sc;
    for (int r = 0; r < GG; r++) Ls[r * HF + c] = G2[r * HF + c] * sc + sh;
    __syncthreads();
    for (int o = c; o < GG * CC; o += HF) {
        int r = o / CC, j = o % CC;
        float acc = bcls[j];
        for (int k = 0; k < HF; k++) acc += Ls[r * HF + k] * Wcls[k * CC + j];
        scratch[o] = acc;
    }
    __threadfence_block();
    __syncthreads();
    int r = c;
    float m = -1e30f;
    for (int j = 0; j < CC; j++) m = fmaxf(m, scratch[r * CC + j]);
    float se = 0.f;
    for (int j = 0; j < CC; j++) se += expf(scratch[r * CC + j] - m);
    float ls = logf(se);
    for (int j = 0; j < CC; j++) outp[r * CC + j] = scratch[r * CC + j] - m - ls;
}

extern "C" void kernel_launch(void* const* d_in, const int* in_sizes, int n_in,
                              void* d_out, int out_size, void* d_ws, size_t ws_size,
                              hipStream_t stream) {
    const float* x         = (const float*)d_in[0];
    const int*   ei        = (const int*)d_in[1];
    const int*   batch     = (const int*)d_in[2];
    const float* bn_feat_g = (const float*)d_in[3];
    const float* bn_feat_b = (const float*)d_in[4];
    const float* W_feat    = (const float*)d_in[5];
    const float* conv_bn_g = (const float*)d_in[6];
    const float* conv_bn_b = (const float*)d_in[7];
    const float* conv_W    = (const float*)d_in[8];
    const float* conv_b    = (const float*)d_in[9];
    const float* bn_fc_g   = (const float*)d_in[10];
    const float* bn_fc_b   = (const float*)d_in[11];
    const float* W_fc      = (const float*)d_in[12];
    const float* b_fc      = (const float*)d_in[13];
    const float* bn_hid_g  = (const float*)d_in[14];
    const float* bn_hid_b  = (const float*)d_in[15];
    const float* W_cls     = (const float*)d_in[16];
    const float* b_cls     = (const float*)d_in[17];
    float* outp = (float*)d_out;

    int N = in_sizes[0] / HF;
    int E = in_sizes[1] / 2;

    char* w = (char*)d_ws;
    size_t off = 0;
    auto al = [&](size_t bytes) -> void* {
        off = (off + 255) & ~(size_t)255;
        void* p = w + off;
        off += bytes;
        return p;
    };
    unsigned short* A  = (unsigned short*)al((size_t)N * HF * 2);   // bf16 node features
    unsigned char*  Bf = (unsigned char*)al((size_t)N * HF);        // int8 y = h@W gather table
    float* rowscl = (float*)al((size_t)N * 4);                       // per-row int8 scale
    int2*  epk    = (int2*)al((size_t)E * 8);
    float* dis    = (float*)al((size_t)N * 4);
    int*   offsb  = (int*)al((size_t)N * 4);
    int*   cursor = (int*)al((size_t)N * 4);
    unsigned short* Wtb = (unsigned short*)al(HF * HF * 2);
    float* biasT  = (float*)al(HF * 4);
    int*   bsum   = (int*)al(1024);
    int*   bscan  = (int*)al(1024);
    float* Gbn    = (float*)al(GG * HF * 4);
    float* G2     = (float*)al(GG * HF * 4);
    // zeroed region
    size_t z0 = (off + 255) & ~(size_t)255;
    off = z0;
    int*   cs    = (int*)al((size_t)N * 4);
    int*   cd    = (int*)al((size_t)N * 4);
    float* Sx    = (float*)al(2 * HF * 4);
    float* S0    = (float*)al(2 * HF * 4);
    float* S1    = (float*)al(2 * HF * 4);
    float* S2    = (float*)al(2 * HF * 4);
    float* gpool = (float*)al(GG * HF * 4);
    size_t zbytes = off - z0;
    hipMemsetAsync(w + z0, 0, zbytes, stream);

    int nbE = (E + 255) / 256;
    int nbN = (N + 255) / 256;

    // graph build
    k_count<<<nbE, 256, 0, stream>>>(ei, E, cs, cd);
    k_scan1<<<nbN, 256, 0, stream>>>(cd, cs, dis, offsb, bsum, N);
    k_scan2<<<1, 256, 0, stream>>>(bsum, bscan, nbN);
    k_scan3<<<nbN, 256, 0, stream>>>(offsb, bscan, cursor, N);
    k_fill<<<nbE, 256, 0, stream>>>(ei, E, dis, cursor, epk);

    // BN(x) stats
    k_colstats<<<400, 256, 0, stream>>>(x, Sx, N);

    int gemmGrid = (N + 127) / 128;

    // feat layer: h0 = relu(bn(x) @ W_feat) -> A (bf16), fused stats -> S0
    k_foldbias<<<HF, HF, 0, stream>>>(Sx, 1.0f / N, bn_feat_g, bn_feat_b, W_feat, Wtb, biasT);
    k_mgemm<1, 1, 1, 0><<<gemmGrid, 256, 0, stream>>>(x, Wtb, biasT, A, nullptr, N, S0);

    float* Sarr[3] = {S0, S1, S2};
    for (int i = 0; i < 3; i++) {
        k_foldbias<<<HF, HF, 0, stream>>>(Sarr[i], 1.0f / N, conv_bn_g + i * HF, conv_bn_b + i * HF,
                                          conv_W + (size_t)i * HF * HF, Wtb, biasT);
        k_mgemm<0, 0, 0, 1><<<gemmGrid, 256, 0, stream>>>(A, Wtb, biasT, Bf, rowscl, N, nullptr);
        if (i < 2)
            k_agg<1><<<(N + 15) / 16, 256, 0, stream>>>(Bf, rowscl, epk, offsb, cd, dis,
                                                        conv_b + i * HF, A, Sarr[i + 1], N);
        else
            k_agg<0><<<(N + 15) / 16, 256, 0, stream>>>(Bf, rowscl, epk, offsb, cd, dis,
                                                        conv_b + i * HF, A, nullptr, N);
    }

    // pool + head
    k_pool<<<GG * 4, 256, 0, stream>>>(A, batch, gpool, N);
    k_bnsmall<<<1, HF, 0, stream>>>(gpool, bn_fc_g, bn_fc_b, Gbn);
    k_fc<<<GG, HF, 0, stream>>>(Gbn, W_fc, b_fc, G2);
    k_head2<<<1, HF, 0, stream>>>(G2, bn_hid_g, bn_hid_b, W_cls, b_cls, Gbn, outp);
}

// Round 8
// 465.423 us; speedup vs baseline: 2.8035x; 1.1567x over previous
//
#include <hip/hip_runtime.h>
#include <hip/hip_bf16.h>

#define HF 128
#define GG 128
#define CC 10
#define EPS 1e-5f

typedef __attribute__((ext_vector_type(8))) short short8;
typedef __attribute__((ext_vector_type(4))) float f32x4;

__device__ inline unsigned short f2bf(float f) {
    unsigned int u = __float_as_uint(f);
    return (unsigned short)((u + 0x7FFFu + ((u >> 16) & 1u)) >> 16);
}

__device__ inline float bf2f(unsigned short h) {
    return __uint_as_float(((unsigned int)h) << 16);
}

// acc[0..7] += w * sext_int8x8(u)
__device__ inline void i8acc(float* acc, unsigned int x, unsigned int y, float w) {
    acc[0] = fmaf(w, (float)((int)(x << 24) >> 24), acc[0]);
    acc[1] = fmaf(w, (float)((int)(x << 16) >> 24), acc[1]);
    acc[2] = fmaf(w, (float)((int)(x << 8) >> 24), acc[2]);
    acc[3] = fmaf(w, (float)((int)x >> 24), acc[3]);
    acc[4] = fmaf(w, (float)((int)(y << 24) >> 24), acc[4]);
    acc[5] = fmaf(w, (float)((int)(y << 16) >> 24), acc[5]);
    acc[6] = fmaf(w, (float)((int)(y << 8) >> 24), acc[6]);
    acc[7] = fmaf(w, (float)((int)y >> 24), acc[7]);
}

// acc[0..15] += w * sext_int8x16(u)
__device__ inline void i8acc16(float* acc, uint4 u, float w) {
    i8acc(acc, u.x, u.y, w);
    i8acc(acc + 8, u.z, u.w, w);
}

__device__ inline unsigned int pk4i8(float a, float b, float c, float d, float inv) {
    int q0 = (int)rintf(a * inv), q1 = (int)rintf(b * inv);
    int q2 = (int)rintf(c * inv), q3 = (int)rintf(d * inv);
    return (unsigned int)(q0 & 255) | ((unsigned int)(q1 & 255) << 8) |
           ((unsigned int)(q2 & 255) << 16) | ((unsigned int)(q3 & 255) << 24);
}

// ---------------- graph build ----------------
__global__ void k_count(const int* __restrict__ ei, int E, int* cs, int* cd) {
    int e = blockIdx.x * 256 + threadIdx.x;
    if (e < E) {
        atomicAdd(&cs[ei[e]], 1);
        atomicAdd(&cd[ei[E + e]], 1);
    }
}

__global__ void k_scan1(const int* __restrict__ cd, const int* __restrict__ cs,
                        float* __restrict__ dis, int* offs, int* bsum, int n) {
    __shared__ int sh[256];
    int t = threadIdx.x, i = blockIdx.x * 256 + t;
    if (i < n) dis[i] = rsqrtf((float)(1 + cs[i]));
    int v = (i < n) ? cd[i] : 0;
    sh[t] = v; __syncthreads();
    for (int o = 1; o < 256; o <<= 1) {
        int x = (t >= o) ? sh[t - o] : 0;
        __syncthreads();
        sh[t] += x;
        __syncthreads();
    }
    if (i < n) offs[i] = sh[t] - v;
    if (t == 255) bsum[blockIdx.x] = sh[255];
}

__global__ void k_scan2(const int* __restrict__ bsum, int* bscan, int nb) {
    __shared__ int sh[256];
    int t = threadIdx.x;
    int v = (t < nb) ? bsum[t] : 0;
    sh[t] = v; __syncthreads();
    for (int o = 1; o < 256; o <<= 1) {
        int x = (t >= o) ? sh[t - o] : 0;
        __syncthreads();
        sh[t] += x;
        __syncthreads();
    }
    if (t < nb) bscan[t] = sh[t] - v;
}

__global__ void k_scan3(int* offs, const int* __restrict__ bscan, int* cursor, int n) {
    int i = blockIdx.x * 256 + threadIdx.x;
    if (i < n) {
        int v = offs[i] + bscan[blockIdx.x];
        offs[i] = v;
        cursor[i] = v;
    }
}

__global__ void k_fill(const int* __restrict__ ei, int E, const float* __restrict__ dis,
                       int* cursor, int2* __restrict__ epk) {
    int e = blockIdx.x * 256 + threadIdx.x;
    if (e < E) {
        int s = ei[e], d = ei[E + e];
        int p = atomicAdd(&cursor[d], 1);
        epk[p] = make_int2(s, __float_as_int(dis[s] * dis[d]));
    }
}

// ---------------- BN stats over x ----------------
__global__ void k_colstats(const float* __restrict__ X, float* stats, int n) {
    int c = threadIdx.x & 127, rl = threadIdx.x >> 7;
    float s = 0.f, q = 0.f;
    for (int i = blockIdx.x * 2 + rl; i < n; i += gridDim.x * 2) {
        float v = X[(size_t)i * HF + c];
        s += v; q += v * v;
    }
    __shared__ float sh[512];
    sh[threadIdx.x] = s; sh[256 + threadIdx.x] = q;
    __syncthreads();
    if (threadIdx.x < 128) {
        atomicAdd(&stats[c],      sh[threadIdx.x] + sh[threadIdx.x + 128]);
        atomicAdd(&stats[HF + c], sh[256 + threadIdx.x] + sh[256 + threadIdx.x + 128]);
    }
}

// ------- BN fold -------
__global__ void k_foldbias(const float* __restrict__ stats, float cntInv,
                           const float* __restrict__ g, const float* __restrict__ b,
                           const float* __restrict__ W, unsigned short* __restrict__ Wtb,
                           float* __restrict__ biasT) {
    int n = blockIdx.x, k = threadIdx.x;
    float mean = stats[k] * cntInv;
    float var = stats[HF + k] * cntInv - mean * mean;
    float sc = g[k] * rsqrtf(var + EPS);
    float shf = b[k] - mean * sc;
    float wkn = W[k * HF + n];
    Wtb[n * HF + k] = f2bf(sc * wkn);
    __shared__ float red[128];
    red[k] = shf * wkn;
    __syncthreads();
    for (int o = 64; o > 0; o >>= 1) {
        if (k < o) red[k] += red[k + o];
        __syncthreads();
    }
    if (k == 0) biasT[n] = red[0];
}

// ---------------- MFMA GEMM: out = A @ Wt^T + biasT ----------------
// 256 threads = 4 waves, 32 rows/wave, 128 rows/block.
// OUTQ=1: int8 rows (128B) + per-row scale into rowscl. OUTQ=0: bf16 rows (256B).
template <int XIN, int RELU, int STATS, int OUTQ>
__global__ __launch_bounds__(256) void k_mgemm(const void* __restrict__ Ain,
                                               const unsigned short* __restrict__ Wtb,
                                               const float* __restrict__ biasT,
                                               void* __restrict__ outv,
                                               float* __restrict__ rowscl,
                                               int n, float* stats) {
    __shared__ float Ls[4][16 * 128];   // 32 KB: per-wave transpose tile
    __shared__ float bsh[128];
    int l = threadIdx.x & 63, w = threadIdx.x >> 6;
    int lr = l & 15, lc = l >> 4;
    int rowbase = blockIdx.x * 128 + w * 32;
    if (threadIdx.x < 128) bsh[threadIdx.x] = biasT[threadIdx.x];

    f32x4 acc[2][8];
#pragma unroll
    for (int rt = 0; rt < 2; rt++)
#pragma unroll
        for (int nt = 0; nt < 8; nt++) acc[rt][nt] = (f32x4){0.f, 0.f, 0.f, 0.f};

    union U { uint4 u; short8 s; };

    for (int ks = 0; ks < 4; ks++) {
        short8 af[2];
#pragma unroll
        for (int rt = 0; rt < 2; rt++) {
            int row = rowbase + rt * 16 + lr;
            if (XIN) {
                if (row < n) {
                    const float4* xp = (const float4*)((const float*)Ain + (size_t)row * HF + ks * 32 + lc * 8);
                    float4 v0 = xp[0], v1 = xp[1];
                    short8 a;
                    a[0] = (short)f2bf(v0.x); a[1] = (short)f2bf(v0.y);
                    a[2] = (short)f2bf(v0.z); a[3] = (short)f2bf(v0.w);
                    a[4] = (short)f2bf(v1.x); a[5] = (short)f2bf(v1.y);
                    a[6] = (short)f2bf(v1.z); a[7] = (short)f2bf(v1.w);
                    af[rt] = a;
                } else af[rt] = (short8){0,0,0,0,0,0,0,0};
            } else {
                if (row < n) {
                    U u;
                    u.u = *(const uint4*)((const unsigned short*)Ain + (size_t)row * HF + ks * 32 + lc * 8);
                    af[rt] = u.s;
                } else af[rt] = (short8){0,0,0,0,0,0,0,0};
            }
        }
#pragma unroll
        for (int nt = 0; nt < 8; nt++) {
            U ub;
            ub.u = *(const uint4*)(Wtb + (size_t)(nt * 16 + lr) * HF + ks * 32 + lc * 8);
            acc[0][nt] = __builtin_amdgcn_mfma_f32_16x16x32_bf16(af[0], ub.s, acc[0][nt], 0, 0, 0);
            acc[1][nt] = __builtin_amdgcn_mfma_f32_16x16x32_bf16(af[1], ub.s, acc[1][nt], 0, 0, 0);
        }
    }
    __syncthreads();   // bsh ready

    if (STATS) {
        float s[8], q[8];
#pragma unroll
        for (int nt = 0; nt < 8; nt++) { s[nt] = 0.f; q[nt] = 0.f; }
#pragma unroll
        for (int rt = 0; rt < 2; rt++) {
#pragma unroll
            for (int nt = 0; nt < 8; nt++) {
                float bias = bsh[nt * 16 + lr];
#pragma unroll
                for (int r = 0; r < 4; r++) {
                    int row = rowbase + rt * 16 + lc * 4 + r;
                    if (row < n) {
                        float v = acc[rt][nt][r] + bias;
                        if (RELU) v = fmaxf(v, 0.f);
                        s[nt] += v; q[nt] += v * v;
                    }
                }
            }
        }
#pragma unroll
        for (int nt = 0; nt < 8; nt++) {
            s[nt] += __shfl_xor(s[nt], 16);
            q[nt] += __shfl_xor(q[nt], 16);
            s[nt] += __shfl_xor(s[nt], 32);
            q[nt] += __shfl_xor(q[nt], 32);
        }
        if (lc == 0) {
#pragma unroll
            for (int nt = 0; nt < 8; nt++) {
                atomicAdd(&stats[nt * 16 + lr], s[nt]);
                atomicAdd(&stats[HF + nt * 16 + lr], q[nt]);
            }
        }
    }

    // transpose via LDS, coalesced stores
    float* LsW = Ls[w];
    for (int rt = 0; rt < 2; rt++) {
#pragma unroll
        for (int nt = 0; nt < 8; nt++)
#pragma unroll
            for (int r = 0; r < 4; r++)
                LsW[(lc * 4 + r) * 128 + nt * 16 + lr] = acc[rt][nt][r];
        __syncthreads();
        int r16 = l >> 2, cc = (l & 3) * 32;
        int row = rowbase + rt * 16 + r16;
        if (row < n) {
            float v[32];
#pragma unroll
            for (int j = 0; j < 32; j++) {
                float tv = LsW[r16 * 128 + cc + j] + bsh[cc + j];
                if (RELU) tv = fmaxf(tv, 0.f);
                v[j] = tv;
            }
            if (OUTQ) {
                float m = 0.f;
#pragma unroll
                for (int j = 0; j < 32; j++) m = fmaxf(m, fabsf(v[j]));
                m = fmaxf(m, __shfl_xor(m, 1));
                m = fmaxf(m, __shfl_xor(m, 2));
                float inv = (m > 1e-20f) ? 127.f / m : 0.f;
                unsigned int o[8];
#pragma unroll
                for (int j = 0; j < 8; j++)
                    o[j] = pk4i8(v[4 * j], v[4 * j + 1], v[4 * j + 2], v[4 * j + 3], inv);
                uint4* dst = (uint4*)((unsigned char*)outv + (size_t)row * 128 + cc);
                dst[0] = make_uint4(o[0], o[1], o[2], o[3]);
                dst[1] = make_uint4(o[4], o[5], o[6], o[7]);
                if ((l & 3) == 0) rowscl[row] = m * (1.f / 127.f);
            } else {
                unsigned int o[16];
#pragma unroll
                for (int j = 0; j < 16; j++)
                    o[j] = (unsigned int)f2bf(v[2 * j]) | ((unsigned int)f2bf(v[2 * j + 1]) << 16);
                uint4* dst = (uint4*)((unsigned short*)outv + (size_t)row * HF + cc);
                dst[0] = make_uint4(o[0], o[1], o[2], o[3]);
                dst[1] = make_uint4(o[4], o[5], o[6], o[7]);
                dst[2] = make_uint4(o[8], o[9], o[10], o[11]);
                dst[3] = make_uint4(o[12], o[13], o[14], o[15]);
            }
        }
        __syncthreads();
    }
}

// ------- aggregation: out[i] = relu(scl_i*dis2*y[i] + sum_e w*scl_s*y[src] + conv_b) -------
// y rows int8 (128B) + per-row scale. 8 lanes/node (uint4 = 16 ch), 32 nodes/block,
// 8-deep pipelined edge chunks -> 64 row-requests in flight per wave.
template <int STATS>
__global__ __launch_bounds__(256) void k_agg(const unsigned char* __restrict__ B,
                                             const float* __restrict__ rsc,
                                             const int2* __restrict__ epk,
                                             const int* __restrict__ offs,
                                             const int* __restrict__ cnt,
                                             const float* __restrict__ dis,
                                             const float* __restrict__ convb,
                                             unsigned short* __restrict__ out,
                                             float* stats, int n) {
    int t = threadIdx.x;
    int lg = t & 7;                       // 16-byte chunk of the 128B row
    int node = blockIdx.x * 32 + (t >> 3);
    const uint4* Bv = (const uint4*)B;    // row = node*8 + lg
    float acc[16];
#pragma unroll
    for (int k = 0; k < 16; k++) acc[k] = 0.f;
    float v[16];
    if (node < n) {
        float d = dis[node];
        i8acc16(acc, Bv[(size_t)node * 8 + lg], d * d * rsc[node]);
        int j = offs[node], e0 = j + cnt[node];
        int2 p[8]; float sp[8];
#pragma unroll
        for (int u = 0; u < 8; u++) p[u] = (j + u < e0) ? epk[j + u] : make_int2(node, 0);
#pragma unroll
        for (int u = 0; u < 8; u++) sp[u] = rsc[p[u].x];
        while (j < e0) {
            uint4 g0 = Bv[(size_t)p[0].x * 8 + lg];
            uint4 g1 = Bv[(size_t)p[1].x * 8 + lg];
            uint4 g2 = Bv[(size_t)p[2].x * 8 + lg];
            uint4 g3 = Bv[(size_t)p[3].x * 8 + lg];
            uint4 g4 = Bv[(size_t)p[4].x * 8 + lg];
            uint4 g5 = Bv[(size_t)p[5].x * 8 + lg];
            uint4 g6 = Bv[(size_t)p[6].x * 8 + lg];
            uint4 g7 = Bv[(size_t)p[7].x * 8 + lg];
            int jn = j + 8;
            int2 pn[8]; float spn[8];
#pragma unroll
            for (int u = 0; u < 8; u++) pn[u] = (jn + u < e0) ? epk[jn + u] : make_int2(node, 0);
#pragma unroll
            for (int u = 0; u < 8; u++) spn[u] = rsc[pn[u].x];
            i8acc16(acc, g0, __int_as_float(p[0].y) * sp[0]);
            i8acc16(acc, g1, __int_as_float(p[1].y) * sp[1]);
            i8acc16(acc, g2, __int_as_float(p[2].y) * sp[2]);
            i8acc16(acc, g3, __int_as_float(p[3].y) * sp[3]);
            i8acc16(acc, g4, __int_as_float(p[4].y) * sp[4]);
            i8acc16(acc, g5, __int_as_float(p[5].y) * sp[5]);
            i8acc16(acc, g6, __int_as_float(p[6].y) * sp[6]);
            i8acc16(acc, g7, __int_as_float(p[7].y) * sp[7]);
#pragma unroll
            for (int u = 0; u < 8; u++) { p[u] = pn[u]; sp[u] = spn[u]; }
            j = jn;
        }
        const float4* cb = (const float4*)convb;   // channels lg*16 .. lg*16+15
        float4 b0 = cb[lg * 4], b1 = cb[lg * 4 + 1], b2 = cb[lg * 4 + 2], b3 = cb[lg * 4 + 3];
        v[0]  = fmaxf(acc[0]  + b0.x, 0.f); v[1]  = fmaxf(acc[1]  + b0.y, 0.f);
        v[2]  = fmaxf(acc[2]  + b0.z, 0.f); v[3]  = fmaxf(acc[3]  + b0.w, 0.f);
        v[4]  = fmaxf(acc[4]  + b1.x, 0.f); v[5]  = fmaxf(acc[5]  + b1.y, 0.f);
        v[6]  = fmaxf(acc[6]  + b1.z, 0.f); v[7]  = fmaxf(acc[7]  + b1.w, 0.f);
        v[8]  = fmaxf(acc[8]  + b2.x, 0.f); v[9]  = fmaxf(acc[9]  + b2.y, 0.f);
        v[10] = fmaxf(acc[10] + b2.z, 0.f); v[11] = fmaxf(acc[11] + b2.w, 0.f);
        v[12] = fmaxf(acc[12] + b3.x, 0.f); v[13] = fmaxf(acc[13] + b3.y, 0.f);
        v[14] = fmaxf(acc[14] + b3.z, 0.f); v[15] = fmaxf(acc[15] + b3.w, 0.f);
        uint4 o0, o1;
        o0.x = (unsigned int)f2bf(v[0])  | ((unsigned int)f2bf(v[1])  << 16);
        o0.y = (unsigned int)f2bf(v[2])  | ((unsigned int)f2bf(v[3])  << 16);
        o0.z = (unsigned int)f2bf(v[4])  | ((unsigned int)f2bf(v[5])  << 16);
        o0.w = (unsigned int)f2bf(v[6])  | ((unsigned int)f2bf(v[7])  << 16);
        o1.x = (unsigned int)f2bf(v[8])  | ((unsigned int)f2bf(v[9])  << 16);
        o1.y = (unsigned int)f2bf(v[10]) | ((unsigned int)f2bf(v[11]) << 16);
        o1.z = (unsigned int)f2bf(v[12]) | ((unsigned int)f2bf(v[13]) << 16);
        o1.w = (unsigned int)f2bf(v[14]) | ((unsigned int)f2bf(v[15]) << 16);
        uint4* op = (uint4*)out + (size_t)node * 16 + lg * 2;
        op[0] = o0; op[1] = o1;
    } else {
#pragma unroll
        for (int k = 0; k < 16; k++) v[k] = 0.f;
    }
    if (STATS) {
        __shared__ float sh[4096];   // [32 nodes][128 ch] = 16 KB
        int nb = t >> 3;
#pragma unroll
        for (int k = 0; k < 16; k++) sh[nb * 128 + lg * 16 + k] = v[k];
        __syncthreads();
        if (t < 128) {
            float ts = 0.f, tq = 0.f;
            for (int g = 0; g < 32; g++) {
                float val = sh[g * 128 + t];
                ts += val; tq += val * val;
            }
            atomicAdd(&stats[t], ts);
            atomicAdd(&stats[HF + t], tq);
        }
    }
}

// ---------------- global add pool ----------------
__global__ __launch_bounds__(256) void k_pool(const unsigned short* __restrict__ A,
                                              const int* __restrict__ batch,
                                              float* gpool, int n) {
    int g = blockIdx.x >> 2, part = blockIdx.x & 3;
    int lo, hi;
    {
        int l = 0, r = n;
        while (l < r) { int m = (l + r) >> 1; if (batch[m] < g) l = m + 1; else r = m; }
        lo = l;
    }
    {
        int l = lo, r = n;
        while (l < r) { int m = (l + r) >> 1; if (batch[m] < g + 1) l = m + 1; else r = m; }
        hi = l;
    }
    int cntg = hi - lo;
    if (cntg <= 0) return;
    int per = (cntg + 3) >> 2;
    int s = lo + part * per, e = min(s + per, hi);
    int c2 = threadIdx.x & 63;
    int rl = threadIdx.x >> 6;
    float a0 = 0.f, a1 = 0.f;
    for (int i = s + rl; i < e; i += 4) {
        unsigned int u = ((const unsigned int*)(A + (size_t)i * HF))[c2];
        a0 += bf2f((unsigned short)(u & 0xFFFFu));
        a1 += bf2f((unsigned short)(u >> 16));
    }
    __shared__ float sh[512];
    sh[rl * 128 + c2 * 2] = a0;
    sh[rl * 128 + c2 * 2 + 1] = a1;
    __syncthreads();
    if (threadIdx.x < 128 && s < hi) {
        float s4 = sh[threadIdx.x] + sh[128 + threadIdx.x] + sh[256 + threadIdx.x] + sh[384 + threadIdx.x];
        atomicAdd(&gpool[g * HF + threadIdx.x], s4);
    }
}

// ---------------- head ----------------
__global__ void k_bnsmall(const float* __restrict__ in, const float* __restrict__ g,
                          const float* __restrict__ b, float* out) {
    int c = threadIdx.x;
    float s = 0.f, q = 0.f;
    for (int r = 0; r < GG; r++) { float v = in[r * HF + c]; s += v; q += v * v; }
    float mean = s / GG;
    float var = q / GG - mean * mean;
    float sc = g[c] * rsqrtf(var + EPS), sh = b[c] - mean * sc;
    for (int r = 0; r < GG; r++) out[r * HF + c] = in[r * HF + c] * sc + sh;
}

__global__ void k_fc(const float* __restrict__ Gbn, const float* __restrict__ Wfc,
                     const float* __restrict__ bfc, float* __restrict__ G2) {
    __shared__ float row[HF];
    int c = threadIdx.x, r = blockIdx.x;
    row[c] = Gbn[r * HF + c];
    __syncthreads();
    float acc = bfc[c];
    for (int k = 0; k < HF; k++) acc += row[k] * Wfc[k * HF + c];
    G2[r * HF + c] = fmaxf(acc, 0.f);
}

__global__ void k_head2(const float* __restrict__ G2, const float* __restrict__ g,
                        const float* __restrict__ b, const float* __restrict__ Wcls,
                        const float* __restrict__ bcls, float* __restrict__ scratch,
                        float* __restrict__ outp) {
    __shared__ float Ls[GG * HF];
    int c = threadIdx.x;
    float s = 0.f, q = 0.f;
    for (int r = 0; r < GG; r++) { float v = G2[r * HF + c]; s += v; q += v * v; }
    float mean = s / GG;
    float var = q / GG - mean * mean;
    float sc = g[c] * rsqrtf(var + EPS), sh = b[c] - mean * sc;
    for (int r = 0; r < GG; r++) Ls[r * HF + c] = G2[r * HF + c] * sc + sh;
    __syncthreads();
    for (int o = c; o < GG * CC; o += HF) {
        int r = o / CC, j = o % CC;
        float acc = bcls[j];
        for (int k = 0; k < HF; k++) acc += Ls[r * HF + k] * Wcls[k * CC + j];
        scratch[o] = acc;
    }
    __threadfence_block();
    __syncthreads();
    int r = c;
    float m = -1e30f;
    for (int j = 0; j < CC; j++) m = fmaxf(m, scratch[r * CC + j]);
    float se = 0.f;
    for (int j = 0; j < CC; j++) se += expf(scratch[r * CC + j] - m);
    float ls = logf(se);
    for (int j = 0; j < CC; j++) outp[r * CC + j] = scratch[r * CC + j] - m - ls;
}

extern "C" void kernel_launch(void* const* d_in, const int* in_sizes, int n_in,
                              void* d_out, int out_size, void* d_ws, size_t ws_size,
                              hipStream_t stream) {
    const float* x         = (const float*)d_in[0];
    const int*   ei        = (const int*)d_in[1];
    const int*   batch     = (const int*)d_in[2];
    const float* bn_feat_g = (const float*)d_in[3];
    const float* bn_feat_b = (const float*)d_in[4];
    const float* W_feat    = (const float*)d_in[5];
    const float* conv_bn_g = (const float*)d_in[6];
    const float* conv_bn_b = (const float*)d_in[7];
    const float* conv_W    = (const float*)d_in[8];
    const float* conv_b    = (const float*)d_in[9];
    const float* bn_fc_g   = (const float*)d_in[10];
    const float* bn_fc_b   = (const float*)d_in[11];
    const float* W_fc      = (const float*)d_in[12];
    const float* b_fc      = (const float*)d_in[13];
    const float* bn_hid_g  = (const float*)d_in[14];
    const float* bn_hid_b  = (const float*)d_in[15];
    const float* W_cls     = (const float*)d_in[16];
    const float* b_cls     = (const float*)d_in[17];
    float* outp = (float*)d_out;

    int N = in_sizes[0] / HF;
    int E = in_sizes[1] / 2;

    char* w = (char*)d_ws;
    size_t off = 0;
    auto al = [&](size_t bytes) -> void* {
        off = (off + 255) & ~(size_t)255;
        void* p = w + off;
        off += bytes;
        return p;
    };
    unsigned short* A  = (unsigned short*)al((size_t)N * HF * 2);   // bf16 node features
    unsigned char*  Bf = (unsigned char*)al((size_t)N * HF);        // int8 y = h@W gather table
    float* rowscl = (float*)al((size_t)N * 4);                       // per-row int8 scale
    int2*  epk    = (int2*)al((size_t)E * 8);
    float* dis    = (float*)al((size_t)N * 4);
    int*   offsb  = (int*)al((size_t)N * 4);
    int*   cursor = (int*)al((size_t)N * 4);
    unsigned short* Wtb = (unsigned short*)al(HF * HF * 2);
    float* biasT  = (float*)al(HF * 4);
    int*   bsum   = (int*)al(1024);
    int*   bscan  = (int*)al(1024);
    float* Gbn    = (float*)al(GG * HF * 4);
    float* G2     = (float*)al(GG * HF * 4);
    // zeroed region
    size_t z0 = (off + 255) & ~(size_t)255;
    off = z0;
    int*   cs    = (int*)al((size_t)N * 4);
    int*   cd    = (int*)al((size_t)N * 4);
    float* Sx    = (float*)al(2 * HF * 4);
    float* S0    = (float*)al(2 * HF * 4);
    float* S1    = (float*)al(2 * HF * 4);
    float* S2    = (float*)al(2 * HF * 4);
    float* gpool = (float*)al(GG * HF * 4);
    size_t zbytes = off - z0;
    hipMemsetAsync(w + z0, 0, zbytes, stream);

    int nbE = (E + 255) / 256;
    int nbN = (N + 255) / 256;

    // graph build
    k_count<<<nbE, 256, 0, stream>>>(ei, E, cs, cd);
    k_scan1<<<nbN, 256, 0, stream>>>(cd, cs, dis, offsb, bsum, N);
    k_scan2<<<1, 256, 0, stream>>>(bsum, bscan, nbN);
    k_scan3<<<nbN, 256, 0, stream>>>(offsb, bscan, cursor, N);
    k_fill<<<nbE, 256, 0, stream>>>(ei, E, dis, cursor, epk);

    // BN(x) stats
    k_colstats<<<400, 256, 0, stream>>>(x, Sx, N);

    int gemmGrid = (N + 127) / 128;

    // feat layer: h0 = relu(bn(x) @ W_feat) -> A (bf16), fused stats -> S0
    k_foldbias<<<HF, HF, 0, stream>>>(Sx, 1.0f / N, bn_feat_g, bn_feat_b, W_feat, Wtb, biasT);
    k_mgemm<1, 1, 1, 0><<<gemmGrid, 256, 0, stream>>>(x, Wtb, biasT, A, nullptr, N, S0);

    float* Sarr[3] = {S0, S1, S2};
    for (int i = 0; i < 3; i++) {
        k_foldbias<<<HF, HF, 0, stream>>>(Sarr[i], 1.0f / N, conv_bn_g + i * HF, conv_bn_b + i * HF,
                                          conv_W + (size_t)i * HF * HF, Wtb, biasT);
        k_mgemm<0, 0, 0, 1><<<gemmGrid, 256, 0, stream>>>(A, Wtb, biasT, Bf, rowscl, N, nullptr);
        if (i < 2)
            k_agg<1><<<(N + 31) / 32, 256, 0, stream>>>(Bf, rowscl, epk, offsb, cd, dis,
                                                        conv_b + i * HF, A, Sarr[i + 1], N);
        else
            k_agg<0><<<(N + 31) / 32, 256, 0, stream>>>(Bf, rowscl, epk, offsb, cd, dis,
                                                        conv_b + i * HF, A, nullptr, N);
    }

    // pool + head
    k_pool<<<GG * 4, 256, 0, stream>>>(A, batch, gpool, N);
    k_bnsmall<<<1, HF, 0, stream>>>(gpool, bn_fc_g, bn_fc_b, Gbn);
    k_fc<<<GG, HF, 0, stream>>>(Gbn, W_fc, b_fc, G2);
    k_head2<<<1, HF, 0, stream>>>(G2, bn_hid_g, bn_hid_b, W_cls, b_cls, Gbn, outp);
}